// Round 2
// baseline (378.215 us; speedup 1.0000x reference)
//
#include <hip/hip_runtime.h>

#define DD 1024
#define NN 16
#define SS 4096
#define BBATCH 8
#define TOK (BBATCH*SS)

typedef __attribute__((ext_vector_type(8))) __bf16 bf16x8;
typedef __attribute__((ext_vector_type(4))) float f32x4;
typedef unsigned int u32;
typedef unsigned long long u64;

__device__ __forceinline__ void async16(void* lds, const void* g) {
  __builtin_amdgcn_global_load_lds(
      (const __attribute__((address_space(1))) u32*)(u64)(g),
      (__attribute__((address_space(3))) u32*)(u32)(u64)(lds), 16, 0, 0);
}

__device__ __forceinline__ float sigmoidf_(float v) {
  return 1.f / (1.f + __expf(-v));
}

// ---------------- f32 -> bf16 convert (vectorized, 8 elems/thread) ----------------
__global__ void k_cvt(const float* __restrict__ in, __bf16* __restrict__ out, int n8) {
  int i = blockIdx.x * blockDim.x + threadIdx.x;
  if (i >= n8) return;
  const float4* in4 = (const float4*)in;
  float4 a = in4[(u64)i * 2 + 0];
  float4 b = in4[(u64)i * 2 + 1];
  bf16x8 o;
  o[0] = (__bf16)a.x; o[1] = (__bf16)a.y; o[2] = (__bf16)a.z; o[3] = (__bf16)a.w;
  o[4] = (__bf16)b.x; o[5] = (__bf16)b.y; o[6] = (__bf16)b.z; o[7] = (__bf16)b.w;
  *(bf16x8*)(out + (u64)i * 8) = o;
}

// ---------------- projection: [lam|Bx](32768x32) = x_bf16 @ Wproj^T ----------------
// BM=128, BN=32, BK=32, 4 waves (256 thr). Wproj rows 0-15 = W_lambda, 16-31 = W_B.
__global__ __launch_bounds__(256)
void k_proj(const __bf16* __restrict__ xb, const __bf16* __restrict__ wp,
            const float* __restrict__ b_lambda,
            float* __restrict__ lam, float* __restrict__ bx) {
  __shared__ __align__(16) __bf16 sA[128 * 32];
  __shared__ __align__(16) __bf16 sB[32 * 32];
  int tid = threadIdx.x;
  int lane = tid & 63, w = tid >> 6;
  int tok0 = blockIdx.x * 128;
  u64 aSrc[2];
#pragma unroll
  for (int q = 0; q < 2; ++q) {
    int u = q * 256 + tid;
    int row = u >> 2, slot = (u & 3) ^ (row & 3);
    aSrc[q] = (u64)((const char*)xb + ((u64)(tok0 + row) * DD + slot * 8) * 2);
  }
  u64 bSrc;
  {
    int u = tid;
    int row = u >> 2, slot = (u & 3) ^ (row & 3);
    bSrc = (u64)((const char*)wp + ((u64)row * DD + slot * 8) * 2);
  }
  f32x4 acc[2][2] = {};
  int r15 = lane & 15, kg = lane >> 4;
  for (int kt = 0; kt < DD / 32; ++kt) {
#pragma unroll
    for (int q = 0; q < 2; ++q)
      async16((char*)sA + (q * 256 + w * 64) * 16, (const void*)(aSrc[q] + kt * 64));
    if (tid < 128)
      async16((char*)sB + w * 1024, (const void*)(bSrc + kt * 64));
    __syncthreads();
    bf16x8 bfr[2];
#pragma unroll
    for (int nt = 0; nt < 2; ++nt) {
      int brow = nt * 16 + r15;
      bfr[nt] = *(const bf16x8*)((const char*)sB + brow * 64 + ((kg ^ (brow & 3)) << 4));
    }
#pragma unroll
    for (int mt = 0; mt < 2; ++mt) {
      int arow = w * 32 + mt * 16 + r15;
      bf16x8 af = *(const bf16x8*)((const char*)sA + arow * 64 + ((kg ^ (arow & 3)) << 4));
#pragma unroll
      for (int nt = 0; nt < 2; ++nt)
        acc[mt][nt] = __builtin_amdgcn_mfma_f32_16x16x32_bf16(af, bfr[nt], acc[mt][nt], 0, 0, 0);
    }
    __syncthreads();
  }
#pragma unroll
  for (int mt = 0; mt < 2; ++mt)
#pragma unroll
    for (int nt = 0; nt < 2; ++nt)
#pragma unroll
      for (int r = 0; r < 4; ++r) {
        int token = tok0 + w * 32 + mt * 16 + kg * 4 + r;
        int j = nt * 16 + r15;
        float v = acc[mt][nt][r];
        if (j < 16) lam[token * NN + j] = sigmoidf_(v + b_lambda[j]);
        else        bx[token * NN + (j - 16)] = v;
      }
}

// ---------------- chunked parallel scan: h_t = lam_t*h_{t-1} + Bx_t ----------------
__global__ __launch_bounds__(256)
void k_scan(const float* __restrict__ lam, const float* __restrict__ bx,
            float* __restrict__ hs) {
  int b = blockIdx.x >> 4, n = blockIdx.x & 15;
  int t = threadIdx.x;
  const int CH = SS / 256;  // 16
  float lv[CH], bv[CH];
  int base = (b * SS + t * CH) * NN + n;
  float a = 1.f, bacc = 0.f;
#pragma unroll
  for (int i = 0; i < CH; ++i) {
    lv[i] = lam[base + i * NN];
    bv[i] = bx[base + i * NN];
    bacc = lv[i] * bacc + bv[i];
    a *= lv[i];
  }
  __shared__ float As[2][256], Bs[2][256];
  As[0][t] = a; Bs[0][t] = bacc;
  __syncthreads();
  int cur = 0;
  for (int off = 1; off < 256; off <<= 1) {
    float a2 = As[cur][t], b2 = Bs[cur][t];
    if (t >= off) {
      float ap = As[cur][t - off], bp = Bs[cur][t - off];
      b2 = b2 + a2 * bp;
      a2 = a2 * ap;
    }
    As[cur ^ 1][t] = a2; Bs[cur ^ 1][t] = b2;
    cur ^= 1;
    __syncthreads();
  }
  float h = (t == 0) ? 0.f : Bs[cur][t - 1];
#pragma unroll
  for (int i = 0; i < CH; ++i) {
    h = lv[i] * h + bv[i];
    hs[base + i * NN] = h;
  }
}

// ---------------- gate GEMM (128x128xK=1024) + fused sigmoid*(C@h) epilogue ----------------
// 4 waves (256 thr); wave (wr,wc) owns 64x64; acc[4][4] f32x4. Writes y f32 to d_out.
__global__ __launch_bounds__(256)
void k_gemm(const __bf16* __restrict__ xb, const __bf16* __restrict__ wg,
            const float* __restrict__ hs, const float* __restrict__ wc,
            float* __restrict__ out) {
  __shared__ __align__(16) union {
    struct { __bf16 A[128 * 32]; __bf16 B[128 * 32]; } st;     // 8KB + 8KB
    struct { float hsl[128 * 16]; float wcl[128 * 17]; } ep;   // 8KB + 8.5KB
  } sm;
  int tid = threadIdx.x, lane = tid & 63, w = tid >> 6;
  int bid = blockIdx.x;
  int swz = (bid & 7) * 256 + (bid >> 3);   // bijective XCD swizzle (2048 % 8 == 0)
  int m = swz >> 3, n = swz & 7;            // consecutive swz share m-panel -> x L2 reuse
  int tok0 = m * 128, n0 = n * 128;
  int r15 = lane & 15, kg = lane >> 4;
  int wr = w >> 1, wcq = w & 1;
  u64 aSrc[2], bSrc[2];
#pragma unroll
  for (int q = 0; q < 2; ++q) {
    int u = q * 256 + tid;
    int row = u >> 2, slot = (u & 3) ^ (row & 3);
    aSrc[q] = (u64)((const char*)xb + ((u64)(tok0 + row) * DD + slot * 8) * 2);
    bSrc[q] = (u64)((const char*)wg + ((u64)(n0 + row) * DD + slot * 8) * 2);
  }
  f32x4 acc[4][4] = {};
  for (int kt = 0; kt < DD / 32; ++kt) {
#pragma unroll
    for (int q = 0; q < 2; ++q) {
      async16((char*)sm.st.A + (q * 256 + w * 64) * 16, (const void*)(aSrc[q] + kt * 64));
      async16((char*)sm.st.B + (q * 256 + w * 64) * 16, (const void*)(bSrc[q] + kt * 64));
    }
    __syncthreads();
    bf16x8 af[4];
#pragma unroll
    for (int mt = 0; mt < 4; ++mt) {
      int arow = wr * 64 + mt * 16 + r15;
      af[mt] = *(const bf16x8*)((const char*)sm.st.A + arow * 64 + ((kg ^ (arow & 3)) << 4));
    }
#pragma unroll
    for (int nt = 0; nt < 4; ++nt) {
      int brow = wcq * 64 + nt * 16 + r15;
      bf16x8 bfr = *(const bf16x8*)((const char*)sm.st.B + brow * 64 + ((kg ^ (brow & 3)) << 4));
#pragma unroll
      for (int mt = 0; mt < 4; ++mt)
        acc[mt][nt] = __builtin_amdgcn_mfma_f32_16x16x32_bf16(af[mt], bfr, acc[mt][nt], 0, 0, 0);
    }
    __syncthreads();
  }
  // ---- epilogue: stage hs tile + W_C tile, compute y = sigmoid(G) * (C@h) ----
  for (int idx = tid; idx < 128 * 16; idx += 256)
    sm.ep.hsl[idx] = hs[(u64)tok0 * NN + idx];
  for (int idx = tid; idx < 128 * 16; idx += 256) {
    int d = idx >> 4, nn2 = idx & 15;
    sm.ep.wcl[d * 17 + nn2] = wc[(u64)(n0 + d) * NN + nn2];
  }
  __syncthreads();
#pragma unroll
  for (int mt = 0; mt < 4; ++mt)
#pragma unroll
    for (int r = 0; r < 4; ++r) {
      int i = wr * 64 + mt * 16 + kg * 4 + r;
#pragma unroll
      for (int nt = 0; nt < 4; ++nt) {
        int j = wcq * 64 + nt * 16 + r15;
        float cy = 0.f;
#pragma unroll
        for (int nn2 = 0; nn2 < NN; ++nn2)
          cy += sm.ep.hsl[i * NN + nn2] * sm.ep.wcl[j * 17 + nn2];
        float g = sigmoidf_(acc[mt][nt][r]);
        out[(u64)(tok0 + i) * DD + n0 + j] = g * cy;
      }
    }
}

// ---------------- in-place RMSNorm over d_out: one wave per row ----------------
__global__ __launch_bounds__(256)
void k_norm(float* __restrict__ out, const float* __restrict__ rw) {
  int row = blockIdx.x * 4 + (threadIdx.x >> 6);
  int lane = threadIdx.x & 63;
  float4* p = (float4*)(out + (u64)row * DD) + lane * 4;
  float4 v[4];
  float rs = 0.f;
#pragma unroll
  for (int e = 0; e < 4; ++e) {
    v[e] = p[e];
    rs += v[e].x * v[e].x + v[e].y * v[e].y + v[e].z * v[e].z + v[e].w * v[e].w;
  }
#pragma unroll
  for (int msk = 1; msk < 64; msk <<= 1) rs += __shfl_xor(rs, msk, 64);
  float rstd = rsqrtf(rs * (1.f / DD) + 1e-6f);
  const float4* rwp = (const float4*)rw + lane * 4;
#pragma unroll
  for (int e = 0; e < 4; ++e) {
    float4 wv = rwp[e];
    float4 o;
    o.x = v[e].x * rstd * wv.x;
    o.y = v[e].y * rstd * wv.y;
    o.z = v[e].z * rstd * wv.z;
    o.w = v[e].w * rstd * wv.w;
    p[e] = o;
  }
}

extern "C" void kernel_launch(void* const* d_in, const int* in_sizes, int n_in,
                              void* d_out, int out_size, void* d_ws, size_t ws_size,
                              hipStream_t stream) {
  (void)in_sizes; (void)n_in; (void)out_size; (void)ws_size;
  const float* x        = (const float*)d_in[0];
  const float* W_lambda = (const float*)d_in[1];
  const float* b_lambda = (const float*)d_in[2];
  const float* W_B      = (const float*)d_in[3];
  const float* W_C      = (const float*)d_in[4];
  const float* W_gate   = (const float*)d_in[5];
  const float* rms_w    = (const float*)d_in[6];
  char* ws = (char*)d_ws;
  __bf16* xb  = (__bf16*)(ws + 0);           // 67108864 B
  __bf16* wg  = (__bf16*)(ws + 67108864);    // 2097152 B
  __bf16* wp  = (__bf16*)(ws + 69206016);    // 65536 B
  float*  lam = (float*)(ws + 69271552);     // 2097152 B
  float*  bx  = (float*)(ws + 71368704);     // 2097152 B
  float*  hs  = (float*)(ws + 73465856);     // 2097152 B
  float*  out = (float*)d_out;

  k_cvt<<<TOK * DD / 8 / 256, 256, 0, stream>>>(x, xb, TOK * DD / 8);
  k_cvt<<<DD * DD / 8 / 256, 256, 0, stream>>>(W_gate, wg, DD * DD / 8);
  k_cvt<<<NN * DD / 8 / 256, 256, 0, stream>>>(W_lambda, wp, NN * DD / 8);
  k_cvt<<<NN * DD / 8 / 256, 256, 0, stream>>>(W_B, wp + NN * DD, NN * DD / 8);
  k_proj<<<TOK / 128, 256, 0, stream>>>(xb, wp, b_lambda, lam, bx);
  k_scan<<<BBATCH * NN, 256, 0, stream>>>(lam, bx, hs);
  k_gemm<<<(TOK / 128) * (DD / 128), 256, 0, stream>>>(xb, wg, hs, W_C, out);
  k_norm<<<TOK / 4, 256, 0, stream>>>(out, rms_w);
}

// Round 3
// 220.484 us; speedup vs baseline: 1.7154x; 1.7154x over previous
//
#include <hip/hip_runtime.h>

#define DD 1024
#define NN 16
#define SS 4096
#define BBATCH 8
#define TOK (BBATCH*SS)

typedef __attribute__((ext_vector_type(8))) __bf16 bf16x8;
typedef __attribute__((ext_vector_type(4))) float f32x4;
typedef unsigned int u32;
typedef unsigned long long u64;

__device__ __forceinline__ void async16(void* lds, const void* g) {
  __builtin_amdgcn_global_load_lds(
      (const __attribute__((address_space(1))) u32*)(u64)(g),
      (__attribute__((address_space(3))) u32*)(u32)(u64)(lds), 16, 0, 0);
}

__device__ __forceinline__ float sigmoidf_(float v) {
  return 1.f / (1.f + __expf(-v));
}

// ---------------- f32 -> bf16 convert (vectorized, 8 elems/thread) ----------------
__global__ void k_cvt(const float* __restrict__ in, __bf16* __restrict__ out, int n8) {
  int i = blockIdx.x * blockDim.x + threadIdx.x;
  if (i >= n8) return;
  const float4* in4 = (const float4*)in;
  float4 a = in4[(u64)i * 2 + 0];
  float4 b = in4[(u64)i * 2 + 1];
  bf16x8 o;
  o[0] = (__bf16)a.x; o[1] = (__bf16)a.y; o[2] = (__bf16)a.z; o[3] = (__bf16)a.w;
  o[4] = (__bf16)b.x; o[5] = (__bf16)b.y; o[6] = (__bf16)b.z; o[7] = (__bf16)b.w;
  *(bf16x8*)(out + (u64)i * 8) = o;
}

// ---------------- projection: [lam|Bx](32768x32) = x_bf16 @ Wproj^T ----------------
__global__ __launch_bounds__(256)
void k_proj(const __bf16* __restrict__ xb, const __bf16* __restrict__ wp,
            const float* __restrict__ b_lambda,
            float* __restrict__ lam, float* __restrict__ bx) {
  __shared__ __align__(16) __bf16 sA[128 * 32];
  __shared__ __align__(16) __bf16 sB[32 * 32];
  int tid = threadIdx.x;
  int lane = tid & 63, w = tid >> 6;
  int tok0 = blockIdx.x * 128;
  u64 aSrc[2];
#pragma unroll
  for (int q = 0; q < 2; ++q) {
    int u = q * 256 + tid;
    int row = u >> 2, slot = (u & 3) ^ (row & 3);
    aSrc[q] = (u64)((const char*)xb + ((u64)(tok0 + row) * DD + slot * 8) * 2);
  }
  u64 bSrc;
  {
    int u = tid;
    int row = u >> 2, slot = (u & 3) ^ (row & 3);
    bSrc = (u64)((const char*)wp + ((u64)row * DD + slot * 8) * 2);
  }
  f32x4 acc[2][2] = {};
  int r15 = lane & 15, kg = lane >> 4;
  for (int kt = 0; kt < DD / 32; ++kt) {
#pragma unroll
    for (int q = 0; q < 2; ++q)
      async16((char*)sA + (q * 256 + w * 64) * 16, (const void*)(aSrc[q] + kt * 64));
    if (tid < 128)
      async16((char*)sB + w * 1024, (const void*)(bSrc + kt * 64));
    __syncthreads();
    bf16x8 bfr[2];
#pragma unroll
    for (int nt = 0; nt < 2; ++nt) {
      int brow = nt * 16 + r15;
      bfr[nt] = *(const bf16x8*)((const char*)sB + brow * 64 + ((kg ^ (brow & 3)) << 4));
    }
#pragma unroll
    for (int mt = 0; mt < 2; ++mt) {
      int arow = w * 32 + mt * 16 + r15;
      bf16x8 af = *(const bf16x8*)((const char*)sA + arow * 64 + ((kg ^ (arow & 3)) << 4));
#pragma unroll
      for (int nt = 0; nt < 2; ++nt)
        acc[mt][nt] = __builtin_amdgcn_mfma_f32_16x16x32_bf16(af, bfr[nt], acc[mt][nt], 0, 0, 0);
    }
    __syncthreads();
  }
#pragma unroll
  for (int mt = 0; mt < 2; ++mt)
#pragma unroll
    for (int nt = 0; nt < 2; ++nt)
#pragma unroll
      for (int r = 0; r < 4; ++r) {
        int token = tok0 + w * 32 + mt * 16 + kg * 4 + r;
        int j = nt * 16 + r15;
        float v = acc[mt][nt][r];
        if (j < 16) lam[token * NN + j] = sigmoidf_(v + b_lambda[j]);
        else        bx[token * NN + (j - 16)] = v;
      }
}

// ---------------- chunked parallel scan: h_t = lam_t*h_{t-1} + Bx_t ----------------
__global__ __launch_bounds__(256)
void k_scan(const float* __restrict__ lam, const float* __restrict__ bx,
            float* __restrict__ hs) {
  int b = blockIdx.x >> 4, n = blockIdx.x & 15;
  int t = threadIdx.x;
  const int CH = SS / 256;  // 16
  float lv[CH], bv[CH];
  int base = (b * SS + t * CH) * NN + n;
  float a = 1.f, bacc = 0.f;
#pragma unroll
  for (int i = 0; i < CH; ++i) {
    lv[i] = lam[base + i * NN];
    bv[i] = bx[base + i * NN];
    bacc = lv[i] * bacc + bv[i];
    a *= lv[i];
  }
  __shared__ float As[2][256], Bs[2][256];
  As[0][t] = a; Bs[0][t] = bacc;
  __syncthreads();
  int cur = 0;
  for (int off = 1; off < 256; off <<= 1) {
    float a2 = As[cur][t], b2 = Bs[cur][t];
    if (t >= off) {
      float ap = As[cur][t - off], bp = Bs[cur][t - off];
      b2 = b2 + a2 * bp;
      a2 = a2 * ap;
    }
    As[cur ^ 1][t] = a2; Bs[cur ^ 1][t] = b2;
    cur ^= 1;
    __syncthreads();
  }
  float h = (t == 0) ? 0.f : Bs[cur][t - 1];
#pragma unroll
  for (int i = 0; i < CH; ++i) {
    h = lv[i] * h + bv[i];
    hs[base + i * NN] = h;
  }
}

// ---------------- gate GEMM (128x128xK=1024) + fused sigmoid*(C@h) epilogue ----------------
// 4 waves; wave (wr,wc) owns 64x64; launch_bounds(256,3) caps VGPR<=170 -> 3 waves/SIMD.
__global__ __launch_bounds__(256, 3)
void k_gemm(const __bf16* __restrict__ xb, const __bf16* __restrict__ wg,
            const float* __restrict__ hs, const float* __restrict__ wc,
            float* __restrict__ out) {
  __shared__ __align__(16) union {
    struct { __bf16 A[128 * 32]; __bf16 B[128 * 32]; } st;   // 8KB + 8KB
    struct { float hsl[128 * 16]; float wcl[128 * 16]; } ep; // 8KB + 8KB
  } sm;
  int tid = threadIdx.x, lane = tid & 63, w = tid >> 6;
  int bid = blockIdx.x;
  int swz = (bid & 7) * 256 + (bid >> 3);   // bijective XCD swizzle (2048 % 8 == 0)
  int m = swz >> 3, n = swz & 7;
  int tok0 = m * 128, n0 = n * 128;
  int r15 = lane & 15, kg = lane >> 4;
  int wr = w >> 1, wcq = w & 1;
  u64 aSrc[2], bSrc[2];
#pragma unroll
  for (int q = 0; q < 2; ++q) {
    int u = q * 256 + tid;
    int row = u >> 2, slot = (u & 3) ^ (row & 3);
    aSrc[q] = (u64)((const char*)xb + ((u64)(tok0 + row) * DD + slot * 8) * 2);
    bSrc[q] = (u64)((const char*)wg + ((u64)(n0 + row) * DD + slot * 8) * 2);
  }
  f32x4 acc[4][4] = {};
  for (int kt = 0; kt < DD / 32; ++kt) {
#pragma unroll
    for (int q = 0; q < 2; ++q) {
      async16((char*)sm.st.A + (q * 256 + w * 64) * 16, (const void*)(aSrc[q] + kt * 64));
      async16((char*)sm.st.B + (q * 256 + w * 64) * 16, (const void*)(bSrc[q] + kt * 64));
    }
    __syncthreads();
    bf16x8 af[4];
#pragma unroll
    for (int mt = 0; mt < 4; ++mt) {
      int arow = wr * 64 + mt * 16 + r15;
      af[mt] = *(const bf16x8*)((const char*)sm.st.A + arow * 64 + ((kg ^ (arow & 3)) << 4));
    }
#pragma unroll
    for (int nt = 0; nt < 4; ++nt) {
      int brow = wcq * 64 + nt * 16 + r15;
      bf16x8 bfr = *(const bf16x8*)((const char*)sm.st.B + brow * 64 + ((kg ^ (brow & 3)) << 4));
#pragma unroll
      for (int mt = 0; mt < 4; ++mt)
        acc[mt][nt] = __builtin_amdgcn_mfma_f32_16x16x32_bf16(af[mt], bfr, acc[mt][nt], 0, 0, 0);
    }
    __syncthreads();
  }
  // ---- epilogue: y = sigmoid(G) * (C@h), vectorized LDS ----
  for (int idx = tid; idx < 128 * 16; idx += 256)
    sm.ep.hsl[idx] = hs[(u64)tok0 * NN + idx];
  for (int idx = tid; idx < 128 * 16; idx += 256)
    sm.ep.wcl[idx] = wc[(u64)n0 * NN + idx];   // W_C is (D,N) row-major: rows n0..n0+127
  __syncthreads();
  f32x4 wcv[4][4];
#pragma unroll
  for (int nt = 0; nt < 4; ++nt) {
    int j = wcq * 64 + nt * 16 + r15;
#pragma unroll
    for (int q = 0; q < 4; ++q)
      wcv[nt][q] = *(const f32x4*)(&sm.ep.wcl[j * 16 + q * 4]);
  }
#pragma unroll
  for (int mt = 0; mt < 4; ++mt)
#pragma unroll
    for (int r = 0; r < 4; ++r) {
      int i = wr * 64 + mt * 16 + kg * 4 + r;
      f32x4 hv[4];
#pragma unroll
      for (int q = 0; q < 4; ++q)
        hv[q] = *(const f32x4*)(&sm.ep.hsl[i * 16 + q * 4]);
#pragma unroll
      for (int nt = 0; nt < 4; ++nt) {
        f32x4 cv = hv[0] * wcv[nt][0];
        cv += hv[1] * wcv[nt][1];
        cv += hv[2] * wcv[nt][2];
        cv += hv[3] * wcv[nt][3];
        float cy = cv[0] + cv[1] + cv[2] + cv[3];
        float g = sigmoidf_(acc[mt][nt][r]);
        int j = wcq * 64 + nt * 16 + r15;
        out[(u64)(tok0 + i) * DD + n0 + j] = g * cy;
      }
    }
}

// ---------------- in-place RMSNorm over d_out: one wave per row (coalesced) ----------------
__global__ __launch_bounds__(256)
void k_norm(float* __restrict__ out, const float* __restrict__ rw) {
  int row = blockIdx.x * 4 + (threadIdx.x >> 6);
  int lane = threadIdx.x & 63;
  float4* p = (float4*)(out + (u64)row * DD);
  float4 v[4];
  float rs = 0.f;
#pragma unroll
  for (int e = 0; e < 4; ++e) {
    v[e] = p[e * 64 + lane];
    rs += v[e].x * v[e].x + v[e].y * v[e].y + v[e].z * v[e].z + v[e].w * v[e].w;
  }
#pragma unroll
  for (int msk = 1; msk < 64; msk <<= 1) rs += __shfl_xor(rs, msk, 64);
  float rstd = rsqrtf(rs * (1.f / DD) + 1e-6f);
  const float4* rwp = (const float4*)rw;
#pragma unroll
  for (int e = 0; e < 4; ++e) {
    float4 wv = rwp[e * 64 + lane];
    float4 o;
    o.x = v[e].x * rstd * wv.x;
    o.y = v[e].y * rstd * wv.y;
    o.z = v[e].z * rstd * wv.z;
    o.w = v[e].w * rstd * wv.w;
    p[e * 64 + lane] = o;
  }
}

extern "C" void kernel_launch(void* const* d_in, const int* in_sizes, int n_in,
                              void* d_out, int out_size, void* d_ws, size_t ws_size,
                              hipStream_t stream) {
  (void)in_sizes; (void)n_in; (void)out_size; (void)ws_size;
  const float* x        = (const float*)d_in[0];
  const float* W_lambda = (const float*)d_in[1];
  const float* b_lambda = (const float*)d_in[2];
  const float* W_B      = (const float*)d_in[3];
  const float* W_C      = (const float*)d_in[4];
  const float* W_gate   = (const float*)d_in[5];
  const float* rms_w    = (const float*)d_in[6];
  char* ws = (char*)d_ws;
  __bf16* xb  = (__bf16*)(ws + 0);           // 67108864 B
  __bf16* wg  = (__bf16*)(ws + 67108864);    // 2097152 B
  __bf16* wp  = (__bf16*)(ws + 69206016);    // 65536 B
  float*  lam = (float*)(ws + 69271552);     // 2097152 B
  float*  bx  = (float*)(ws + 71368704);     // 2097152 B
  float*  hs  = (float*)(ws + 73465856);     // 2097152 B
  float*  out = (float*)d_out;

  k_cvt<<<TOK * DD / 8 / 256, 256, 0, stream>>>(x, xb, TOK * DD / 8);
  k_cvt<<<DD * DD / 8 / 256, 256, 0, stream>>>(W_gate, wg, DD * DD / 8);
  k_cvt<<<NN * DD / 8 / 256, 256, 0, stream>>>(W_lambda, wp, NN * DD / 8);
  k_cvt<<<NN * DD / 8 / 256, 256, 0, stream>>>(W_B, wp + NN * DD, NN * DD / 8);
  k_proj<<<TOK / 128, 256, 0, stream>>>(xb, wp, b_lambda, lam, bx);
  k_scan<<<BBATCH * NN, 256, 0, stream>>>(lam, bx, hs);
  k_gemm<<<(TOK / 128) * (DD / 128), 256, 0, stream>>>(xb, wg, hs, W_C, out);
  k_norm<<<TOK / 4, 256, 0, stream>>>(out, rms_w);
}

// Round 4
// 209.740 us; speedup vs baseline: 1.8033x; 1.0512x over previous
//
#include <hip/hip_runtime.h>

#define DD 1024
#define NN 16
#define SS 4096
#define BBATCH 8
#define TOK (BBATCH*SS)

typedef __attribute__((ext_vector_type(8))) __bf16 bf16x8;
typedef __attribute__((ext_vector_type(4))) float f32x4;
typedef unsigned int u32;
typedef unsigned long long u64;

__device__ __forceinline__ void async16(void* lds, const void* g) {
  __builtin_amdgcn_global_load_lds(
      (const __attribute__((address_space(1))) u32*)(u64)(g),
      (__attribute__((address_space(3))) u32*)(u32)(u64)(lds), 16, 0, 0);
}

__device__ __forceinline__ float sigmoidf_(float v) {
  return 1.f / (1.f + __expf(-v));
}

// ---------------- f32 -> bf16 convert (vectorized, 8 elems/thread) ----------------
__global__ void k_cvt(const float* __restrict__ in, __bf16* __restrict__ out, int n8) {
  int i = blockIdx.x * blockDim.x + threadIdx.x;
  if (i >= n8) return;
  const float4* in4 = (const float4*)in;
  float4 a = in4[(u64)i * 2 + 0];
  float4 b = in4[(u64)i * 2 + 1];
  bf16x8 o;
  o[0] = (__bf16)a.x; o[1] = (__bf16)a.y; o[2] = (__bf16)a.z; o[3] = (__bf16)a.w;
  o[4] = (__bf16)b.x; o[5] = (__bf16)b.y; o[6] = (__bf16)b.z; o[7] = (__bf16)b.w;
  *(bf16x8*)(out + (u64)i * 8) = o;
}

// ---------------- projection: [lam|Bx](32768x32) = x_bf16 @ Wproj^T ----------------
__global__ __launch_bounds__(256)
void k_proj(const __bf16* __restrict__ xb, const __bf16* __restrict__ wp,
            const float* __restrict__ b_lambda,
            float* __restrict__ lam, float* __restrict__ bx) {
  __shared__ __align__(16) __bf16 sA[128 * 32];
  __shared__ __align__(16) __bf16 sB[32 * 32];
  int tid = threadIdx.x;
  int lane = tid & 63, w = tid >> 6;
  int tok0 = blockIdx.x * 128;
  u64 aSrc[2];
#pragma unroll
  for (int q = 0; q < 2; ++q) {
    int u = q * 256 + tid;
    int row = u >> 2, slot = (u & 3) ^ (row & 3);
    aSrc[q] = (u64)((const char*)xb + ((u64)(tok0 + row) * DD + slot * 8) * 2);
  }
  u64 bSrc;
  {
    int u = tid;
    int row = u >> 2, slot = (u & 3) ^ (row & 3);
    bSrc = (u64)((const char*)wp + ((u64)row * DD + slot * 8) * 2);
  }
  f32x4 acc[2][2] = {};
  int r15 = lane & 15, kg = lane >> 4;
  for (int kt = 0; kt < DD / 32; ++kt) {
#pragma unroll
    for (int q = 0; q < 2; ++q)
      async16((char*)sA + (q * 256 + w * 64) * 16, (const void*)(aSrc[q] + kt * 64));
    if (tid < 128)
      async16((char*)sB + w * 1024, (const void*)(bSrc + kt * 64));
    __syncthreads();
    bf16x8 bfr[2];
#pragma unroll
    for (int nt = 0; nt < 2; ++nt) {
      int brow = nt * 16 + r15;
      bfr[nt] = *(const bf16x8*)((const char*)sB + brow * 64 + ((kg ^ (brow & 3)) << 4));
    }
#pragma unroll
    for (int mt = 0; mt < 2; ++mt) {
      int arow = w * 32 + mt * 16 + r15;
      bf16x8 af = *(const bf16x8*)((const char*)sA + arow * 64 + ((kg ^ (arow & 3)) << 4));
#pragma unroll
      for (int nt = 0; nt < 2; ++nt)
        acc[mt][nt] = __builtin_amdgcn_mfma_f32_16x16x32_bf16(af, bfr[nt], acc[mt][nt], 0, 0, 0);
    }
    __syncthreads();
  }
#pragma unroll
  for (int mt = 0; mt < 2; ++mt)
#pragma unroll
    for (int nt = 0; nt < 2; ++nt)
#pragma unroll
      for (int r = 0; r < 4; ++r) {
        int token = tok0 + w * 32 + mt * 16 + kg * 4 + r;
        int j = nt * 16 + r15;
        float v = acc[mt][nt][r];
        if (j < 16) lam[token * NN + j] = sigmoidf_(v + b_lambda[j]);
        else        bx[token * NN + (j - 16)] = v;
      }
}

// ---------------- chunked parallel scan: h_t = lam_t*h_{t-1} + Bx_t ----------------
__global__ __launch_bounds__(256)
void k_scan(const float* __restrict__ lam, const float* __restrict__ bx,
            float* __restrict__ hs) {
  int b = blockIdx.x >> 4, n = blockIdx.x & 15;
  int t = threadIdx.x;
  const int CH = SS / 256;  // 16
  float lv[CH], bv[CH];
  int base = (b * SS + t * CH) * NN + n;
  float a = 1.f, bacc = 0.f;
#pragma unroll
  for (int i = 0; i < CH; ++i) {
    lv[i] = lam[base + i * NN];
    bv[i] = bx[base + i * NN];
    bacc = lv[i] * bacc + bv[i];
    a *= lv[i];
  }
  __shared__ float As[2][256], Bs[2][256];
  As[0][t] = a; Bs[0][t] = bacc;
  __syncthreads();
  int cur = 0;
  for (int off = 1; off < 256; off <<= 1) {
    float a2 = As[cur][t], b2 = Bs[cur][t];
    if (t >= off) {
      float ap = As[cur][t - off], bp = Bs[cur][t - off];
      b2 = b2 + a2 * bp;
      a2 = a2 * ap;
    }
    As[cur ^ 1][t] = a2; Bs[cur ^ 1][t] = b2;
    cur ^= 1;
    __syncthreads();
  }
  float h = (t == 0) ? 0.f : Bs[cur][t - 1];
#pragma unroll
  for (int i = 0; i < CH; ++i) {
    h = lv[i] * h + bv[i];
    hs[base + i * NN] = h;
  }
}

// ---------------- gate GEMM 256x256xK=1024, 8 waves (2Mx4N), wave=128x64 ----------------
// BK=32, 4 LDS buffers (128KB), prefetch depth 3, counted vmcnt(8), 1 barrier/K-step.
// Conflict-free swizzle: slot = kg ^ (row&3) ^ ((row>>2)&3), pre-applied to global source.
#define STG(kt, bi) do { u32 lb = (u32)(bi) * 32768u; u64 ko = (u64)(kt) * 64u;          \
    async16(smc + lb + (u32)w * 1024u,              (const void*)(aAddr0 + ko));         \
    async16(smc + lb + (u32)(8 + w) * 1024u,        (const void*)(aAddr1 + ko));         \
    async16(smc + lb + 16384u + (u32)w * 1024u,     (const void*)(bAddr0 + ko));         \
    async16(smc + lb + 16384u + (u32)(8 + w) * 1024u,(const void*)(bAddr1 + ko)); } while (0)

__global__ __launch_bounds__(512, 2)
void k_gemm(const __bf16* __restrict__ xb, const __bf16* __restrict__ wg,
            const float* __restrict__ hs, const float* __restrict__ wc,
            float* __restrict__ out) {
  __shared__ __align__(16) char smc[131072];
  const int tid = threadIdx.x, lane = tid & 63, w = tid >> 6;
  const int r15 = lane & 15, kg = lane >> 4;
  const int wr = w >> 2, wcq = w & 3;   // 2 M-waves x 4 N-waves
  int bid = blockIdx.x;
  int swz = (bid & 7) * 64 + (bid >> 3);   // bijective (512 % 8 == 0)
  int m = swz >> 2, n = swz & 3;
  const int tok0 = m * 256, n0 = n * 256;
  // staging chunk u(q) = (q*8+w)*64 + lane; row = u>>2; pre-swizzled source slot
  const int sslot = (lane & 3) ^ ((lane >> 2) & 3) ^ ((lane >> 4) & 3);
  const int rA0 = w * 16 + (lane >> 2);
  const int rA1 = (8 + w) * 16 + (lane >> 2);
  const u64 aAddr0 = (u64)(const char*)xb + (u64)(tok0 + rA0) * 2048 + (u32)sslot * 16;
  const u64 aAddr1 = (u64)(const char*)xb + (u64)(tok0 + rA1) * 2048 + (u32)sslot * 16;
  const u64 bAddr0 = (u64)(const char*)wg + (u64)(n0 + rA0) * 2048 + (u32)sslot * 16;
  const u64 bAddr1 = (u64)(const char*)wg + (u64)(n0 + rA1) * 2048 + (u32)sslot * 16;

  f32x4 acc[8][4] = {};

  // prologue: stage tiles 0,1,2
  STG(0, 0); STG(1, 1); STG(2, 2);
  asm volatile("s_waitcnt vmcnt(8)" ::: "memory");   // tile 0 landed (mine); barrier makes it global
  __builtin_amdgcn_s_barrier();
  __builtin_amdgcn_sched_barrier(0);

  for (int t = 0; t < 32; ++t) {
    if (t + 3 < 32) STG(t + 3, (t + 3) & 3);
    const char* Ab = smc + (t & 3) * 32768;
    const char* Bb = Ab + 16384;
    bf16x8 af[8];
#pragma unroll
    for (int mt = 0; mt < 8; ++mt) {
      int row = wr * 128 + mt * 16 + r15;
      int sl = kg ^ (row & 3) ^ ((row >> 2) & 3);
      af[mt] = *(const bf16x8*)(Ab + row * 64 + sl * 16);
    }
    __builtin_amdgcn_s_setprio(1);
#pragma unroll
    for (int nt = 0; nt < 4; ++nt) {
      int brow = wcq * 64 + nt * 16 + r15;
      int sl = kg ^ (brow & 3) ^ ((brow >> 2) & 3);
      bf16x8 bfr = *(const bf16x8*)(Bb + brow * 64 + sl * 16);
#pragma unroll
      for (int mt = 0; mt < 8; ++mt)
        acc[mt][nt] = __builtin_amdgcn_mfma_f32_16x16x32_bf16(af[mt], bfr, acc[mt][nt], 0, 0, 0);
    }
    __builtin_amdgcn_s_setprio(0);
    // counted wait: after this, stages t+2,t+3 (8 loads) may remain -> tile t+1 landed
    if (t < 29)       asm volatile("s_waitcnt vmcnt(8)" ::: "memory");
    else if (t == 29) asm volatile("s_waitcnt vmcnt(4)" ::: "memory");
    else              asm volatile("s_waitcnt vmcnt(0)" ::: "memory");
    __builtin_amdgcn_s_barrier();
    __builtin_amdgcn_sched_barrier(0);
  }

  // ---- epilogue: y = sigmoid(G) * (C@h); LDS repurposed (all K-loop reads done) ----
  float* hsl = (float*)smc;            // 256*16 f32 = 16KB
  float* wcl = (float*)(smc + 16384);  // 256*16 f32 = 16KB
  for (int idx = tid; idx < 256 * 16; idx += 512) hsl[idx] = hs[(u64)tok0 * NN + idx];
  for (int idx = tid; idx < 256 * 16; idx += 512) wcl[idx] = wc[(u64)n0 * NN + idx];
  __syncthreads();
  f32x4 wcv[4][4];
#pragma unroll
  for (int nt = 0; nt < 4; ++nt) {
    int j = wcq * 64 + nt * 16 + r15;
#pragma unroll
    for (int q = 0; q < 4; ++q) wcv[nt][q] = *(const f32x4*)(wcl + j * 16 + q * 4);
  }
#pragma unroll
  for (int mt = 0; mt < 8; ++mt)
#pragma unroll
    for (int r = 0; r < 4; ++r) {
      int i = wr * 128 + mt * 16 + kg * 4 + r;
      f32x4 hv[4];
#pragma unroll
      for (int q = 0; q < 4; ++q) hv[q] = *(const f32x4*)(hsl + i * 16 + q * 4);
#pragma unroll
      for (int nt = 0; nt < 4; ++nt) {
        f32x4 cv = hv[0] * wcv[nt][0];
        cv += hv[1] * wcv[nt][1];
        cv += hv[2] * wcv[nt][2];
        cv += hv[3] * wcv[nt][3];
        float cy = cv[0] + cv[1] + cv[2] + cv[3];
        float g = sigmoidf_(acc[mt][nt][r]);
        int j = wcq * 64 + nt * 16 + r15;
        out[(u64)(tok0 + i) * DD + n0 + j] = g * cy;
      }
    }
}

// ---------------- in-place RMSNorm over d_out: one wave per row (coalesced) ----------------
__global__ __launch_bounds__(256)
void k_norm(float* __restrict__ out, const float* __restrict__ rw) {
  int row = blockIdx.x * 4 + (threadIdx.x >> 6);
  int lane = threadIdx.x & 63;
  float4* p = (float4*)(out + (u64)row * DD);
  float4 v[4];
  float rs = 0.f;
#pragma unroll
  for (int e = 0; e < 4; ++e) {
    v[e] = p[e * 64 + lane];
    rs += v[e].x * v[e].x + v[e].y * v[e].y + v[e].z * v[e].z + v[e].w * v[e].w;
  }
#pragma unroll
  for (int msk = 1; msk < 64; msk <<= 1) rs += __shfl_xor(rs, msk, 64);
  float rstd = rsqrtf(rs * (1.f / DD) + 1e-6f);
  const float4* rwp = (const float4*)rw;
#pragma unroll
  for (int e = 0; e < 4; ++e) {
    float4 wv = rwp[e * 64 + lane];
    float4 o;
    o.x = v[e].x * rstd * wv.x;
    o.y = v[e].y * rstd * wv.y;
    o.z = v[e].z * rstd * wv.z;
    o.w = v[e].w * rstd * wv.w;
    p[e * 64 + lane] = o;
  }
}

extern "C" void kernel_launch(void* const* d_in, const int* in_sizes, int n_in,
                              void* d_out, int out_size, void* d_ws, size_t ws_size,
                              hipStream_t stream) {
  (void)in_sizes; (void)n_in; (void)out_size; (void)ws_size;
  const float* x        = (const float*)d_in[0];
  const float* W_lambda = (const float*)d_in[1];
  const float* b_lambda = (const float*)d_in[2];
  const float* W_B      = (const float*)d_in[3];
  const float* W_C      = (const float*)d_in[4];
  const float* W_gate   = (const float*)d_in[5];
  const float* rms_w    = (const float*)d_in[6];
  char* ws = (char*)d_ws;
  __bf16* xb  = (__bf16*)(ws + 0);           // 67108864 B
  __bf16* wg  = (__bf16*)(ws + 67108864);    // 2097152 B
  __bf16* wp  = (__bf16*)(ws + 69206016);    // 65536 B
  float*  lam = (float*)(ws + 69271552);     // 2097152 B
  float*  bx  = (float*)(ws + 71368704);     // 2097152 B
  float*  hs  = (float*)(ws + 73465856);     // 2097152 B
  float*  out = (float*)d_out;

  k_cvt<<<TOK * DD / 8 / 256, 256, 0, stream>>>(x, xb, TOK * DD / 8);
  k_cvt<<<DD * DD / 8 / 256, 256, 0, stream>>>(W_gate, wg, DD * DD / 8);
  k_cvt<<<NN * DD / 8 / 256, 256, 0, stream>>>(W_lambda, wp, NN * DD / 8);
  k_cvt<<<NN * DD / 8 / 256, 256, 0, stream>>>(W_B, wp + NN * DD, NN * DD / 8);
  k_proj<<<TOK / 128, 256, 0, stream>>>(xb, wp, b_lambda, lam, bx);
  k_scan<<<BBATCH * NN, 256, 0, stream>>>(lam, bx, hs);
  k_gemm<<<(TOK / 256) * (DD / 256), 512, 0, stream>>>(xb, wg, hs, W_C, out);
  k_norm<<<TOK / 4, 256, 0, stream>>>(out, rms_w);
}

// Round 6
// 206.197 us; speedup vs baseline: 1.8342x; 1.0172x over previous
//
#include <hip/hip_runtime.h>

#define DD 1024
#define NN 16
#define SS 4096
#define BBATCH 8
#define TOK (BBATCH*SS)

typedef __attribute__((ext_vector_type(8))) __bf16 bf16x8;
typedef __attribute__((ext_vector_type(4))) __bf16 bf16x4;
typedef __attribute__((ext_vector_type(4))) float f32x4;
typedef unsigned int u32;
typedef unsigned long long u64;

__device__ __forceinline__ void async16(void* lds, const void* g) {
  __builtin_amdgcn_global_load_lds(
      (const __attribute__((address_space(1))) u32*)(u64)(g),
      (__attribute__((address_space(3))) u32*)(u32)(u64)(lds), 16, 0, 0);
}

__device__ __forceinline__ float sigmoidf_(float v) {
  return 1.f / (1.f + __expf(-v));
}

// ---------------- merged weight converts: W_gate, W_lambda, W_B -> bf16 ----------------
__global__ void k_cvtw(const float* __restrict__ wgf, const float* __restrict__ wlf,
                       const float* __restrict__ wbf, __bf16* __restrict__ wg,
                       __bf16* __restrict__ wp) {
  int i = blockIdx.x * blockDim.x + threadIdx.x;
  const int NG = DD * DD / 8, NP = NN * DD / 8;
  const float* src; __bf16* dst;
  if (i < NG)           { src = wgf + (u64)i * 8;            dst = wg + (u64)i * 8; }
  else if (i < NG + NP) { int j = i - NG; src = wlf + j * 8; dst = wp + j * 8; }
  else if (i < NG + 2 * NP) { int j = i - NG - NP; src = wbf + j * 8; dst = wp + NN * DD + j * 8; }
  else return;
  float4 a = *(const float4*)src, b = *(const float4*)(src + 4);
  bf16x8 o;
  o[0] = (__bf16)a.x; o[1] = (__bf16)a.y; o[2] = (__bf16)a.z; o[3] = (__bf16)a.w;
  o[4] = (__bf16)b.x; o[5] = (__bf16)b.y; o[6] = (__bf16)b.z; o[7] = (__bf16)b.w;
  *(bf16x8*)dst = o;
}

// ---------------- projection (x f32 -> bf16 fused): [lam|Bx] = x @ Wproj^T ----------------
// BM=128, BN=32, BK=32; also materializes xb (bf16) for k_gemm.
__global__ __launch_bounds__(256)
void k_proj(const float* __restrict__ x, const __bf16* __restrict__ wp,
            const float* __restrict__ b_lambda, __bf16* __restrict__ xb,
            float* __restrict__ lam, float* __restrict__ bx) {
  __shared__ __align__(16) __bf16 sA[128 * 32];
  __shared__ __align__(16) __bf16 sB[32 * 32];
  int tid = threadIdx.x;
  int lane = tid & 63, w = tid >> 6;
  int tok0 = blockIdx.x * 128;
  int crow = tid >> 1, cs = (tid & 1) * 2;
  const float* xsrc = x + (u64)(tok0 + crow) * DD + (tid & 1) * 16;
  __bf16* xdst = xb + (u64)(tok0 + crow) * DD + (tid & 1) * 16;
  int sw = (crow & 3) ^ ((crow >> 2) & 3);
  u64 bSrc;
  {
    int u = tid;
    int row = u >> 2, slot = (u & 3) ^ (row & 3);
    bSrc = (u64)((const char*)wp + ((u64)row * DD + slot * 8) * 2);
  }
  f32x4 acc[2][2] = {};
  int r15 = lane & 15, kg = lane >> 4;
  for (int kt = 0; kt < DD / 32; ++kt) {
    float4 a0 = *(const float4*)(xsrc + kt * 32 + 0);
    float4 a1 = *(const float4*)(xsrc + kt * 32 + 4);
    float4 a2 = *(const float4*)(xsrc + kt * 32 + 8);
    float4 a3 = *(const float4*)(xsrc + kt * 32 + 12);
    bf16x8 lo, hi;
    lo[0] = (__bf16)a0.x; lo[1] = (__bf16)a0.y; lo[2] = (__bf16)a0.z; lo[3] = (__bf16)a0.w;
    lo[4] = (__bf16)a1.x; lo[5] = (__bf16)a1.y; lo[6] = (__bf16)a1.z; lo[7] = (__bf16)a1.w;
    hi[0] = (__bf16)a2.x; hi[1] = (__bf16)a2.y; hi[2] = (__bf16)a2.z; hi[3] = (__bf16)a2.w;
    hi[4] = (__bf16)a3.x; hi[5] = (__bf16)a3.y; hi[6] = (__bf16)a3.z; hi[7] = (__bf16)a3.w;
    *(bf16x8*)(xdst + kt * 32) = lo;
    *(bf16x8*)(xdst + kt * 32 + 8) = hi;
    *(bf16x8*)((char*)sA + crow * 64 + ((cs ^ sw) << 4)) = lo;
    *(bf16x8*)((char*)sA + crow * 64 + (((cs + 1) ^ sw) << 4)) = hi;
    if (tid < 128)
      async16((char*)sB + w * 1024, (const void*)(bSrc + kt * 64));
    __syncthreads();
    bf16x8 bfr[2];
#pragma unroll
    for (int nt = 0; nt < 2; ++nt) {
      int brow = nt * 16 + r15;
      bfr[nt] = *(const bf16x8*)((const char*)sB + brow * 64 + ((kg ^ (brow & 3)) << 4));
    }
#pragma unroll
    for (int mt = 0; mt < 2; ++mt) {
      int arow = w * 32 + mt * 16 + r15;
      bf16x8 af = *(const bf16x8*)((const char*)sA + arow * 64 +
                                   ((kg ^ (arow & 3) ^ ((arow >> 2) & 3)) << 4));
#pragma unroll
      for (int nt = 0; nt < 2; ++nt)
        acc[mt][nt] = __builtin_amdgcn_mfma_f32_16x16x32_bf16(af, bfr[nt], acc[mt][nt], 0, 0, 0);
    }
    __syncthreads();
  }
#pragma unroll
  for (int mt = 0; mt < 2; ++mt)
#pragma unroll
    for (int nt = 0; nt < 2; ++nt)
#pragma unroll
      for (int r = 0; r < 4; ++r) {
        int token = tok0 + w * 32 + mt * 16 + kg * 4 + r;
        int j = nt * 16 + r15;
        float v = acc[mt][nt][r];
        if (j < 16) lam[token * NN + j] = sigmoidf_(v + b_lambda[j]);
        else        bx[token * NN + (j - 16)] = v;
      }
}

// ---------------- chunked parallel scan: h_t = lam_t*h_{t-1} + Bx_t ----------------
__global__ __launch_bounds__(256)
void k_scan(const float* __restrict__ lam, const float* __restrict__ bx,
            float* __restrict__ hs) {
  int b = blockIdx.x >> 4, n = blockIdx.x & 15;
  int t = threadIdx.x;
  const int CH = SS / 256;  // 16
  float lv[CH], bv[CH];
  int base = (b * SS + t * CH) * NN + n;
  float a = 1.f, bacc = 0.f;
#pragma unroll
  for (int i = 0; i < CH; ++i) {
    lv[i] = lam[base + i * NN];
    bv[i] = bx[base + i * NN];
    bacc = lv[i] * bacc + bv[i];
    a *= lv[i];
  }
  __shared__ float As[2][256], Bs[2][256];
  As[0][t] = a; Bs[0][t] = bacc;
  __syncthreads();
  int cur = 0;
  for (int off = 1; off < 256; off <<= 1) {
    float a2 = As[cur][t], b2 = Bs[cur][t];
    if (t >= off) {
      float ap = As[cur][t - off], bp = Bs[cur][t - off];
      b2 = b2 + a2 * bp;
      a2 = a2 * ap;
    }
    As[cur ^ 1][t] = a2; Bs[cur ^ 1][t] = b2;
    cur ^= 1;
    __syncthreads();
  }
  float h = (t == 0) ? 0.f : Bs[cur][t - 1];
#pragma unroll
  for (int i = 0; i < CH; ++i) {
    h = lv[i] * h + bv[i];
    hs[base + i * NN] = h;
  }
}

// ---------------- gate GEMM 256x256xK=1024 — ROUND-4 schedule (known good) ----------------
// 8 waves (2Mx4N), wave=128x64. BK=32, 4 LDS buffers, prefetch depth 3, vmcnt(8), 1 barrier/K.
#define STG(kt, bi) do { u32 lb = (u32)(bi) * 32768u; u64 ko = (u64)(kt) * 64u;          \
    async16(smc + lb + (u32)w * 1024u,              (const void*)(aAddr0 + ko));         \
    async16(smc + lb + (u32)(8 + w) * 1024u,        (const void*)(aAddr1 + ko));         \
    async16(smc + lb + 16384u + (u32)w * 1024u,     (const void*)(bAddr0 + ko));         \
    async16(smc + lb + 16384u + (u32)(8 + w) * 1024u,(const void*)(bAddr1 + ko)); } while (0)

template<int YB16>
__global__ __launch_bounds__(512, 2)
void k_gemm(const __bf16* __restrict__ xb, const __bf16* __restrict__ wg,
            const float* __restrict__ hs, const float* __restrict__ wc,
            float* __restrict__ outf, __bf16* __restrict__ outb) {
  __shared__ __align__(16) char smc[131072];
  const int tid = threadIdx.x, lane = tid & 63, w = tid >> 6;
  const int r15 = lane & 15, kg = lane >> 4;
  const int wr = w >> 2, wcq = w & 3;   // 2 M-waves x 4 N-waves
  int bid = blockIdx.x;
  int swz = (bid & 7) * 64 + (bid >> 3);   // bijective XCD swizzle (512 % 8 == 0)
  int m = swz >> 2, n = swz & 3;
  const int tok0 = m * 256, n0 = n * 256;
  const int sslot = (lane & 3) ^ ((lane >> 2) & 3) ^ ((lane >> 4) & 3);
  const int rA0 = w * 16 + (lane >> 2);
  const int rA1 = (8 + w) * 16 + (lane >> 2);
  const u64 aAddr0 = (u64)(const char*)xb + (u64)(tok0 + rA0) * 2048 + (u32)sslot * 16;
  const u64 aAddr1 = (u64)(const char*)xb + (u64)(tok0 + rA1) * 2048 + (u32)sslot * 16;
  const u64 bAddr0 = (u64)(const char*)wg + (u64)(n0 + rA0) * 2048 + (u32)sslot * 16;
  const u64 bAddr1 = (u64)(const char*)wg + (u64)(n0 + rA1) * 2048 + (u32)sslot * 16;

  f32x4 acc[8][4] = {};

  // prologue: stage tiles 0,1,2
  STG(0, 0); STG(1, 1); STG(2, 2);
  asm volatile("s_waitcnt vmcnt(8)" ::: "memory");   // tile 0 landed (mine); barrier makes it global
  __builtin_amdgcn_s_barrier();
  __builtin_amdgcn_sched_barrier(0);

  for (int t = 0; t < 32; ++t) {
    if (t + 3 < 32) STG(t + 3, (t + 3) & 3);
    const char* Ab = smc + (t & 3) * 32768;
    const char* Bb = Ab + 16384;
    bf16x8 af[8];
#pragma unroll
    for (int mt = 0; mt < 8; ++mt) {
      int row = wr * 128 + mt * 16 + r15;
      int sl = kg ^ (row & 3) ^ ((row >> 2) & 3);
      af[mt] = *(const bf16x8*)(Ab + row * 64 + sl * 16);
    }
    __builtin_amdgcn_s_setprio(1);
#pragma unroll
    for (int nt = 0; nt < 4; ++nt) {
      int brow = wcq * 64 + nt * 16 + r15;
      int sl = kg ^ (brow & 3) ^ ((brow >> 2) & 3);
      bf16x8 bfr = *(const bf16x8*)(Bb + brow * 64 + sl * 16);
#pragma unroll
      for (int mt = 0; mt < 8; ++mt)
        acc[mt][nt] = __builtin_amdgcn_mfma_f32_16x16x32_bf16(af[mt], bfr, acc[mt][nt], 0, 0, 0);
    }
    __builtin_amdgcn_s_setprio(0);
    // counted wait: tiles t+2,t+3 (8 loads) may remain -> tile t+1 landed
    if (t < 29)       asm volatile("s_waitcnt vmcnt(8)" ::: "memory");
    else if (t == 29) asm volatile("s_waitcnt vmcnt(4)" ::: "memory");
    else              asm volatile("s_waitcnt vmcnt(0)" ::: "memory");
    __builtin_amdgcn_s_barrier();
    __builtin_amdgcn_sched_barrier(0);
  }

  // ---- epilogue: y = sigmoid(G) * (C@h); padded LDS (stride 20 f32) ----
  float* hsl = (float*)smc;             // 256*20*4 = 20480 B
  float* wcl = (float*)(smc + 20480);   // 20480 B
  for (int idx = tid; idx < 256 * 16; idx += 512) {
    int r = idx >> 4, c = idx & 15;
    hsl[r * 20 + c] = hs[(u64)tok0 * NN + idx];
    wcl[r * 20 + c] = wc[(u64)n0 * NN + idx];
  }
  __syncthreads();
  f32x4 wcv[4][4];
#pragma unroll
  for (int nt = 0; nt < 4; ++nt) {
    int j = wcq * 64 + nt * 16 + r15;
#pragma unroll
    for (int q = 0; q < 4; ++q) wcv[nt][q] = *(const f32x4*)(wcl + j * 20 + q * 4);
  }
#pragma unroll
  for (int mt = 0; mt < 8; ++mt)
#pragma unroll
    for (int r = 0; r < 4; ++r) {
      int i = wr * 128 + mt * 16 + kg * 4 + r;
      f32x4 hv[4];
#pragma unroll
      for (int q = 0; q < 4; ++q) hv[q] = *(const f32x4*)(hsl + i * 20 + q * 4);
#pragma unroll
      for (int nt = 0; nt < 4; ++nt) {
        f32x4 cv = hv[0] * wcv[nt][0];
        cv += hv[1] * wcv[nt][1];
        cv += hv[2] * wcv[nt][2];
        cv += hv[3] * wcv[nt][3];
        float cy = cv[0] + cv[1] + cv[2] + cv[3];
        float g = sigmoidf_(acc[mt][nt][r]);
        int j = wcq * 64 + nt * 16 + r15;
        u64 off = (u64)(tok0 + i) * DD + n0 + j;
        if (YB16) outb[off] = (__bf16)(g * cy);
        else      outf[off] = g * cy;
      }
    }
}

// ---------------- RMSNorm: read y bf16 (ws), write f32 out (coalesced) ----------------
__global__ __launch_bounds__(256)
void k_norm_b(const __bf16* __restrict__ yb, float* __restrict__ out,
              const float* __restrict__ rw) {
  int row = blockIdx.x * 4 + (threadIdx.x >> 6);
  int lane = threadIdx.x & 63;
  const __bf16* yrow = yb + (u64)row * DD;
  bf16x4 v[4];
  float f[16];
  float rs = 0.f;
#pragma unroll
  for (int q = 0; q < 4; ++q) {
    v[q] = *(const bf16x4*)(yrow + q * 256 + lane * 4);
#pragma unroll
    for (int e = 0; e < 4; ++e) {
      f[q * 4 + e] = (float)v[q][e];
      rs += f[q * 4 + e] * f[q * 4 + e];
    }
  }
#pragma unroll
  for (int msk = 1; msk < 64; msk <<= 1) rs += __shfl_xor(rs, msk, 64);
  float rstd = rsqrtf(rs * (1.f / DD) + 1e-6f);
  float* orow = out + (u64)row * DD;
#pragma unroll
  for (int q = 0; q < 4; ++q) {
    float4 wv = *(const float4*)(rw + q * 256 + lane * 4);
    float4 o;
    o.x = f[q * 4 + 0] * rstd * wv.x;
    o.y = f[q * 4 + 1] * rstd * wv.y;
    o.z = f[q * 4 + 2] * rstd * wv.z;
    o.w = f[q * 4 + 3] * rstd * wv.w;
    *(float4*)(orow + q * 256 + lane * 4) = o;
  }
}

// ---------------- RMSNorm fallback: in-place f32 ----------------
__global__ __launch_bounds__(256)
void k_norm_f(float* __restrict__ out, const float* __restrict__ rw) {
  int row = blockIdx.x * 4 + (threadIdx.x >> 6);
  int lane = threadIdx.x & 63;
  float4* p = (float4*)(out + (u64)row * DD);
  float4 v[4];
  float rs = 0.f;
#pragma unroll
  for (int e = 0; e < 4; ++e) {
    v[e] = p[e * 64 + lane];
    rs += v[e].x * v[e].x + v[e].y * v[e].y + v[e].z * v[e].z + v[e].w * v[e].w;
  }
#pragma unroll
  for (int msk = 1; msk < 64; msk <<= 1) rs += __shfl_xor(rs, msk, 64);
  float rstd = rsqrtf(rs * (1.f / DD) + 1e-6f);
  const float4* rwp = (const float4*)rw;
#pragma unroll
  for (int e = 0; e < 4; ++e) {
    float4 wv = rwp[e * 64 + lane];
    float4 o;
    o.x = v[e].x * rstd * wv.x;
    o.y = v[e].y * rstd * wv.y;
    o.z = v[e].z * rstd * wv.z;
    o.w = v[e].w * rstd * wv.w;
    p[e * 64 + lane] = o;
  }
}

extern "C" void kernel_launch(void* const* d_in, const int* in_sizes, int n_in,
                              void* d_out, int out_size, void* d_ws, size_t ws_size,
                              hipStream_t stream) {
  (void)in_sizes; (void)n_in; (void)out_size;
  const float* x        = (const float*)d_in[0];
  const float* W_lambda = (const float*)d_in[1];
  const float* b_lambda = (const float*)d_in[2];
  const float* W_B      = (const float*)d_in[3];
  const float* W_C      = (const float*)d_in[4];
  const float* W_gate   = (const float*)d_in[5];
  const float* rms_w    = (const float*)d_in[6];
  char* ws = (char*)d_ws;
  __bf16* xb  = (__bf16*)(ws + 0);           // 67108864 B
  __bf16* wg  = (__bf16*)(ws + 67108864);    // 2097152 B
  __bf16* wp  = (__bf16*)(ws + 69206016);    // 65536 B
  float*  lam = (float*)(ws + 69271552);     // 2097152 B
  float*  bx  = (float*)(ws + 71368704);     // 2097152 B
  float*  hs  = (float*)(ws + 73465856);     // 2097152 B
  __bf16* yb  = (__bf16*)(ws + 75563008);    // 67108864 B (optional)
  float*  out = (float*)d_out;
  bool yb16 = ws_size >= (size_t)(75563008ull + 67108864ull);

  k_cvtw<<<(DD * DD / 8 + 2 * NN * DD / 8 + 255) / 256, 256, 0, stream>>>(
      W_gate, W_lambda, W_B, wg, wp);
  k_proj<<<TOK / 128, 256, 0, stream>>>(x, wp, b_lambda, xb, lam, bx);
  k_scan<<<BBATCH * NN, 256, 0, stream>>>(lam, bx, hs);
  if (yb16) {
    k_gemm<1><<<(TOK / 256) * (DD / 256), 512, 0, stream>>>(xb, wg, hs, W_C, nullptr, yb);
    k_norm_b<<<TOK / 4, 256, 0, stream>>>(yb, out, rms_w);
  } else {
    k_gemm<0><<<(TOK / 256) * (DD / 256), 512, 0, stream>>>(xb, wg, hs, W_C, out, nullptr);
    k_norm_f<<<TOK / 4, 256, 0, stream>>>(out, rms_w);
  }
}

// Round 7
// 199.907 us; speedup vs baseline: 1.8920x; 1.0315x over previous
//
#include <hip/hip_runtime.h>

#define DD 1024
#define NN 16
#define SS 4096
#define BBATCH 8
#define TOK (BBATCH*SS)

typedef __attribute__((ext_vector_type(8))) __bf16 bf16x8;
typedef __attribute__((ext_vector_type(4))) __bf16 bf16x4;
typedef __attribute__((ext_vector_type(4))) float f32x4;
typedef unsigned int u32;
typedef unsigned long long u64;

__device__ __forceinline__ void async16(void* lds, const void* g) {
  __builtin_amdgcn_global_load_lds(
      (const __attribute__((address_space(1))) u32*)(u64)(g),
      (__attribute__((address_space(3))) u32*)(u32)(u64)(lds), 16, 0, 0);
}

__device__ __forceinline__ float sigmoidf_(float v) {
  return 1.f / (1.f + __expf(-v));
}

// ---------------- merged weight converts: W_gate, W_lambda, W_B -> bf16 ----------------
__global__ void k_cvtw(const float* __restrict__ wgf, const float* __restrict__ wlf,
                       const float* __restrict__ wbf, __bf16* __restrict__ wg,
                       __bf16* __restrict__ wp) {
  int i = blockIdx.x * blockDim.x + threadIdx.x;
  const int NG = DD * DD / 8, NP = NN * DD / 8;
  const float* src; __bf16* dst;
  if (i < NG)           { src = wgf + (u64)i * 8;            dst = wg + (u64)i * 8; }
  else if (i < NG + NP) { int j = i - NG; src = wlf + j * 8; dst = wp + j * 8; }
  else if (i < NG + 2 * NP) { int j = i - NG - NP; src = wbf + j * 8; dst = wp + NN * DD + j * 8; }
  else return;
  float4 a = *(const float4*)src, b = *(const float4*)(src + 4);
  bf16x8 o;
  o[0] = (__bf16)a.x; o[1] = (__bf16)a.y; o[2] = (__bf16)a.z; o[3] = (__bf16)a.w;
  o[4] = (__bf16)b.x; o[5] = (__bf16)b.y; o[6] = (__bf16)b.z; o[7] = (__bf16)b.w;
  *(bf16x8*)dst = o;
}

// ---------------- projection (x f32 -> bf16 fused): [lam|Bx] = x @ Wproj^T ----------------
__global__ __launch_bounds__(256)
void k_proj(const float* __restrict__ x, const __bf16* __restrict__ wp,
            const float* __restrict__ b_lambda, __bf16* __restrict__ xb,
            float* __restrict__ lam, float* __restrict__ bx) {
  __shared__ __align__(16) __bf16 sA[128 * 32];
  __shared__ __align__(16) __bf16 sB[32 * 32];
  int tid = threadIdx.x;
  int lane = tid & 63, w = tid >> 6;
  int tok0 = blockIdx.x * 128;
  int crow = tid >> 1, cs = (tid & 1) * 2;
  const float* xsrc = x + (u64)(tok0 + crow) * DD + (tid & 1) * 16;
  __bf16* xdst = xb + (u64)(tok0 + crow) * DD + (tid & 1) * 16;
  int sw = (crow & 3) ^ ((crow >> 2) & 3);
  u64 bSrc;
  {
    int u = tid;
    int row = u >> 2, slot = (u & 3) ^ (row & 3);
    bSrc = (u64)((const char*)wp + ((u64)row * DD + slot * 8) * 2);
  }
  f32x4 acc[2][2] = {};
  int r15 = lane & 15, kg = lane >> 4;
  for (int kt = 0; kt < DD / 32; ++kt) {
    float4 a0 = *(const float4*)(xsrc + kt * 32 + 0);
    float4 a1 = *(const float4*)(xsrc + kt * 32 + 4);
    float4 a2 = *(const float4*)(xsrc + kt * 32 + 8);
    float4 a3 = *(const float4*)(xsrc + kt * 32 + 12);
    bf16x8 lo, hi;
    lo[0] = (__bf16)a0.x; lo[1] = (__bf16)a0.y; lo[2] = (__bf16)a0.z; lo[3] = (__bf16)a0.w;
    lo[4] = (__bf16)a1.x; lo[5] = (__bf16)a1.y; lo[6] = (__bf16)a1.z; lo[7] = (__bf16)a1.w;
    hi[0] = (__bf16)a2.x; hi[1] = (__bf16)a2.y; hi[2] = (__bf16)a2.z; hi[3] = (__bf16)a2.w;
    hi[4] = (__bf16)a3.x; hi[5] = (__bf16)a3.y; hi[6] = (__bf16)a3.z; hi[7] = (__bf16)a3.w;
    *(bf16x8*)(xdst + kt * 32) = lo;
    *(bf16x8*)(xdst + kt * 32 + 8) = hi;
    *(bf16x8*)((char*)sA + crow * 64 + ((cs ^ sw) << 4)) = lo;
    *(bf16x8*)((char*)sA + crow * 64 + (((cs + 1) ^ sw) << 4)) = hi;
    if (tid < 128)
      async16((char*)sB + w * 1024, (const void*)(bSrc + kt * 64));
    __syncthreads();
    bf16x8 bfr[2];
#pragma unroll
    for (int nt = 0; nt < 2; ++nt) {
      int brow = nt * 16 + r15;
      bfr[nt] = *(const bf16x8*)((const char*)sB + brow * 64 + ((kg ^ (brow & 3)) << 4));
    }
#pragma unroll
    for (int mt = 0; mt < 2; ++mt) {
      int arow = w * 32 + mt * 16 + r15;
      bf16x8 af = *(const bf16x8*)((const char*)sA + arow * 64 +
                                   ((kg ^ (arow & 3) ^ ((arow >> 2) & 3)) << 4));
#pragma unroll
      for (int nt = 0; nt < 2; ++nt)
        acc[mt][nt] = __builtin_amdgcn_mfma_f32_16x16x32_bf16(af, bfr[nt], acc[mt][nt], 0, 0, 0);
    }
    __syncthreads();
  }
#pragma unroll
  for (int mt = 0; mt < 2; ++mt)
#pragma unroll
    for (int nt = 0; nt < 2; ++nt)
#pragma unroll
      for (int r = 0; r < 4; ++r) {
        int token = tok0 + w * 32 + mt * 16 + kg * 4 + r;
        int j = nt * 16 + r15;
        float v = acc[mt][nt][r];
        if (j < 16) lam[token * NN + j] = sigmoidf_(v + b_lambda[j]);
        else        bx[token * NN + (j - 16)] = v;
      }
}

// ---------------- chunked parallel scan: h_t = lam_t*h_{t-1} + Bx_t ----------------
__global__ __launch_bounds__(256)
void k_scan(const float* __restrict__ lam, const float* __restrict__ bx,
            float* __restrict__ hs) {
  int b = blockIdx.x >> 4, n = blockIdx.x & 15;
  int t = threadIdx.x;
  const int CH = SS / 256;  // 16
  float lv[CH], bv[CH];
  int base = (b * SS + t * CH) * NN + n;
  float a = 1.f, bacc = 0.f;
#pragma unroll
  for (int i = 0; i < CH; ++i) {
    lv[i] = lam[base + i * NN];
    bv[i] = bx[base + i * NN];
    bacc = lv[i] * bacc + bv[i];
    a *= lv[i];
  }
  __shared__ float As[2][256], Bs[2][256];
  As[0][t] = a; Bs[0][t] = bacc;
  __syncthreads();
  int cur = 0;
  for (int off = 1; off < 256; off <<= 1) {
    float a2 = As[cur][t], b2 = Bs[cur][t];
    if (t >= off) {
      float ap = As[cur][t - off], bp = Bs[cur][t - off];
      b2 = b2 + a2 * bp;
      a2 = a2 * ap;
    }
    As[cur ^ 1][t] = a2; Bs[cur ^ 1][t] = b2;
    cur ^= 1;
    __syncthreads();
  }
  float h = (t == 0) ? 0.f : Bs[cur][t - 1];
#pragma unroll
  for (int i = 0; i < CH; ++i) {
    h = lv[i] * h + bv[i];
    hs[base + i * NN] = h;
  }
}

// ---------------- gate GEMM 256x256xK=1024 — 8-phase (4 phases/K-tile, BK=64) ----------------
// 2 LDS buffers x (A,B) x 2 halves(128x64) = 8 x 16KB = 128KB. 8 waves (2Mx4N).
// Stage stream: kP1: A(k+1)h1 | kP2: B(k+2)h0 | kP3: B(k+2)h1 | kP4: A(k+2)h0; vmcnt(6)@P4.
// (A(k+1)h0 staged at (k-1)P4; B(k+1) at (k-1)P2/P3 — tile k+1 landed proof: vmcnt(6)
//  leaves only kP2..kP4 issues in flight.)
// Swizzle (8 slots/row of 128B): LDS[row][s] = global[row][s ^ (row&7)], both sides.
#define STAGE(tile, M, h) do {                                                    \
    u32 lds0 = (u32)(((((tile) & 1) * 4 + (M) * 2 + (h)) << 14) + tid * 16);      \
    u64 g0 = ((M) ? bBase : aBase) + ((u64)(h) << 18) + (u64)(tile) * 128;        \
    async16(smc + lds0, (const void*)g0);                                         \
    async16(smc + lds0 + 8192, (const void*)(g0 + 131072));                       \
  } while (0)

template<int YB16>
__global__ __launch_bounds__(512, 2)
void k_gemm(const __bf16* __restrict__ xb, const __bf16* __restrict__ wg,
            const float* __restrict__ hs, const float* __restrict__ wc,
            float* __restrict__ outf, __bf16* __restrict__ outb) {
  __shared__ __align__(16) char smc[131072];
  const int tid = threadIdx.x, lane = tid & 63, w = tid >> 6;
  const int r15 = lane & 15, kg = lane >> 4;
  const int wr = w >> 2, wcq = w & 3;       // 2 M-waves x 4 N-waves
  int bid = blockIdx.x;
  int swz = (bid & 7) * 64 + (bid >> 3);    // bijective XCD swizzle (512 % 8 == 0)
  int m = swz >> 2, n = swz & 3;
  const int tok0 = m * 256, n0 = n * 256;
  // staging: thread covers half-tile LDS linear tid*16 (+8192); row=tid>>3, slot=tid&7
  const int sslot = (tid & 7) ^ ((tid >> 3) & 7);
  const u64 aBase = (u64)(const char*)xb + (u64)(tok0 + (tid >> 3)) * 2048 + (u32)sslot * 16;
  const u64 bBase = (u64)(const char*)wg + (u64)(n0 + (tid >> 3)) * 2048 + (u32)sslot * 16;
  // frag-read swizzled slot byte offsets (kk=0,1); row&7 == r15&7 for all frag rows
  const u32 sxa0 = (u32)(((0 | kg) ^ (r15 & 7)) * 16);
  const u32 sxa1 = (u32)(((4 | kg) ^ (r15 & 7)) * 16);
  const u32 lrB0 = (u32)((wcq & 1) * 64);

  f32x4 acc[8][4] = {};

  // prologue: tile0 (4 halves) + B1h0,B1h1,A1h0 -> vmcnt(6) => tile0 landed
  STAGE(0, 0, 0); STAGE(0, 0, 1); STAGE(0, 1, 0); STAGE(0, 1, 1);
  STAGE(1, 1, 0); STAGE(1, 1, 1); STAGE(1, 0, 0);
  asm volatile("s_waitcnt vmcnt(6)" ::: "memory");
  __builtin_amdgcn_s_barrier();
  asm volatile("" ::: "memory");

  for (int k = 0; k < 16; ++k) {
    const int b = k & 1;
    const char* Ah = smc + (u32)((b * 4 + wr) << 14);
    const char* Bh = smc + (u32)((b * 4 + 2 + (wcq >> 1)) << 14);
    bf16x8 af[8][2], bfr[4][2];
    // ---- P1: read A m0-1 + B all (12 ds) | stage A(k+1)h1 | MFMA m0-1 ----
#pragma unroll
    for (int mt = 0; mt < 2; ++mt) {
      u32 ro = (u32)(mt * 16 + r15) * 128;
      af[mt][0] = *(const bf16x8*)(Ah + ro + sxa0);
      af[mt][1] = *(const bf16x8*)(Ah + ro + sxa1);
    }
#pragma unroll
    for (int nt = 0; nt < 4; ++nt) {
      u32 ro = (lrB0 + (u32)(nt * 16 + r15)) * 128;
      bfr[nt][0] = *(const bf16x8*)(Bh + ro + sxa0);
      bfr[nt][1] = *(const bf16x8*)(Bh + ro + sxa1);
    }
    if (k <= 14) STAGE(k + 1, 0, 1);
    __builtin_amdgcn_s_barrier();
    asm volatile("s_waitcnt lgkmcnt(0)" ::: "memory");
    __builtin_amdgcn_sched_barrier(0);
    __builtin_amdgcn_s_setprio(1);
#pragma unroll
    for (int mt = 0; mt < 2; ++mt)
#pragma unroll
      for (int nt = 0; nt < 4; ++nt) {
        acc[mt][nt] = __builtin_amdgcn_mfma_f32_16x16x32_bf16(af[mt][0], bfr[nt][0], acc[mt][nt], 0, 0, 0);
        acc[mt][nt] = __builtin_amdgcn_mfma_f32_16x16x32_bf16(af[mt][1], bfr[nt][1], acc[mt][nt], 0, 0, 0);
      }
    __builtin_amdgcn_s_setprio(0);
    __builtin_amdgcn_s_barrier();
    asm volatile("" ::: "memory");
    // ---- P2: read A m2-5 (8 ds) | stage B(k+2)h0 | MFMA m2-3 ----
#pragma unroll
    for (int mt = 2; mt < 6; ++mt) {
      u32 ro = (u32)(mt * 16 + r15) * 128;
      af[mt][0] = *(const bf16x8*)(Ah + ro + sxa0);
      af[mt][1] = *(const bf16x8*)(Ah + ro + sxa1);
    }
    if (k <= 13) STAGE(k + 2, 1, 0);
    __builtin_amdgcn_s_barrier();
    asm volatile("s_waitcnt lgkmcnt(0)" ::: "memory");
    __builtin_amdgcn_sched_barrier(0);
    __builtin_amdgcn_s_setprio(1);
#pragma unroll
    for (int mt = 2; mt < 4; ++mt)
#pragma unroll
      for (int nt = 0; nt < 4; ++nt) {
        acc[mt][nt] = __builtin_amdgcn_mfma_f32_16x16x32_bf16(af[mt][0], bfr[nt][0], acc[mt][nt], 0, 0, 0);
        acc[mt][nt] = __builtin_amdgcn_mfma_f32_16x16x32_bf16(af[mt][1], bfr[nt][1], acc[mt][nt], 0, 0, 0);
      }
    __builtin_amdgcn_s_setprio(0);
    __builtin_amdgcn_s_barrier();
    asm volatile("" ::: "memory");
    // ---- P3: read A m6-7 (4 ds) | stage B(k+2)h1 | MFMA m4-5 ----
#pragma unroll
    for (int mt = 6; mt < 8; ++mt) {
      u32 ro = (u32)(mt * 16 + r15) * 128;
      af[mt][0] = *(const bf16x8*)(Ah + ro + sxa0);
      af[mt][1] = *(const bf16x8*)(Ah + ro + sxa1);
    }
    if (k <= 13) STAGE(k + 2, 1, 1);
    __builtin_amdgcn_s_barrier();
    asm volatile("s_waitcnt lgkmcnt(0)" ::: "memory");
    __builtin_amdgcn_sched_barrier(0);
    __builtin_amdgcn_s_setprio(1);
#pragma unroll
    for (int mt = 4; mt < 6; ++mt)
#pragma unroll
      for (int nt = 0; nt < 4; ++nt) {
        acc[mt][nt] = __builtin_amdgcn_mfma_f32_16x16x32_bf16(af[mt][0], bfr[nt][0], acc[mt][nt], 0, 0, 0);
        acc[mt][nt] = __builtin_amdgcn_mfma_f32_16x16x32_bf16(af[mt][1], bfr[nt][1], acc[mt][nt], 0, 0, 0);
      }
    __builtin_amdgcn_s_setprio(0);
    __builtin_amdgcn_s_barrier();
    asm volatile("" ::: "memory");
    // ---- P4: stage A(k+2)h0 | vmcnt | barrier | MFMA m6-7 ----
    if (k <= 13) STAGE(k + 2, 0, 0);
    if (k <= 13)      asm volatile("s_waitcnt vmcnt(6)" ::: "memory");
    else if (k == 14) asm volatile("s_waitcnt vmcnt(0)" ::: "memory");
    __builtin_amdgcn_s_barrier();
    asm volatile("" ::: "memory");
    __builtin_amdgcn_s_setprio(1);
#pragma unroll
    for (int mt = 6; mt < 8; ++mt)
#pragma unroll
      for (int nt = 0; nt < 4; ++nt) {
        acc[mt][nt] = __builtin_amdgcn_mfma_f32_16x16x32_bf16(af[mt][0], bfr[nt][0], acc[mt][nt], 0, 0, 0);
        acc[mt][nt] = __builtin_amdgcn_mfma_f32_16x16x32_bf16(af[mt][1], bfr[nt][1], acc[mt][nt], 0, 0, 0);
      }
    __builtin_amdgcn_s_setprio(0);
  }
  asm volatile("" ::: "memory");

  // ---- epilogue: y = sigmoid(G) * (C@h); padded LDS (stride 20 f32) ----
  float* hsl = (float*)smc;             // 256*20*4 = 20480 B
  float* wcl = (float*)(smc + 20480);   // 20480 B
  for (int idx = tid; idx < 256 * 16; idx += 512) {
    int r = idx >> 4, c = idx & 15;
    hsl[r * 20 + c] = hs[(u64)tok0 * NN + idx];
    wcl[r * 20 + c] = wc[(u64)n0 * NN + idx];
  }
  __syncthreads();
  f32x4 wcv[4][4];
#pragma unroll
  for (int nt = 0; nt < 4; ++nt) {
    int j = wcq * 64 + nt * 16 + r15;
#pragma unroll
    for (int q = 0; q < 4; ++q) wcv[nt][q] = *(const f32x4*)(wcl + j * 20 + q * 4);
  }
#pragma unroll
  for (int mt = 0; mt < 8; ++mt)
#pragma unroll
    for (int r = 0; r < 4; ++r) {
      int i = wr * 128 + mt * 16 + kg * 4 + r;
      f32x4 hv[4];
#pragma unroll
      for (int q = 0; q < 4; ++q) hv[q] = *(const f32x4*)(hsl + i * 20 + q * 4);
#pragma unroll
      for (int nt = 0; nt < 4; ++nt) {
        f32x4 cv = hv[0] * wcv[nt][0];
        cv += hv[1] * wcv[nt][1];
        cv += hv[2] * wcv[nt][2];
        cv += hv[3] * wcv[nt][3];
        float cy = cv[0] + cv[1] + cv[2] + cv[3];
        float g = sigmoidf_(acc[mt][nt][r]);
        int j = wcq * 64 + nt * 16 + r15;
        u64 off = (u64)(tok0 + i) * DD + n0 + j;
        if (YB16) outb[off] = (__bf16)(g * cy);
        else      outf[off] = g * cy;
      }
    }
}

// ---------------- RMSNorm: read y bf16 (ws), write f32 out (coalesced) ----------------
__global__ __launch_bounds__(256)
void k_norm_b(const __bf16* __restrict__ yb, float* __restrict__ out,
              const float* __restrict__ rw) {
  int row = blockIdx.x * 4 + (threadIdx.x >> 6);
  int lane = threadIdx.x & 63;
  const __bf16* yrow = yb + (u64)row * DD;
  bf16x4 v[4];
  float f[16];
  float rs = 0.f;
#pragma unroll
  for (int q = 0; q < 4; ++q) {
    v[q] = *(const bf16x4*)(yrow + q * 256 + lane * 4);
#pragma unroll
    for (int e = 0; e < 4; ++e) {
      f[q * 4 + e] = (float)v[q][e];
      rs += f[q * 4 + e] * f[q * 4 + e];
    }
  }
#pragma unroll
  for (int msk = 1; msk < 64; msk <<= 1) rs += __shfl_xor(rs, msk, 64);
  float rstd = rsqrtf(rs * (1.f / DD) + 1e-6f);
  float* orow = out + (u64)row * DD;
#pragma unroll
  for (int q = 0; q < 4; ++q) {
    float4 wv = *(const float4*)(rw + q * 256 + lane * 4);
    float4 o;
    o.x = f[q * 4 + 0] * rstd * wv.x;
    o.y = f[q * 4 + 1] * rstd * wv.y;
    o.z = f[q * 4 + 2] * rstd * wv.z;
    o.w = f[q * 4 + 3] * rstd * wv.w;
    *(float4*)(orow + q * 256 + lane * 4) = o;
  }
}

// ---------------- RMSNorm fallback: in-place f32 ----------------
__global__ __launch_bounds__(256)
void k_norm_f(float* __restrict__ out, const float* __restrict__ rw) {
  int row = blockIdx.x * 4 + (threadIdx.x >> 6);
  int lane = threadIdx.x & 63;
  float4* p = (float4*)(out + (u64)row * DD);
  float4 v[4];
  float rs = 0.f;
#pragma unroll
  for (int e = 0; e < 4; ++e) {
    v[e] = p[e * 64 + lane];
    rs += v[e].x * v[e].x + v[e].y * v[e].y + v[e].z * v[e].z + v[e].w * v[e].w;
  }
#pragma unroll
  for (int msk = 1; msk < 64; msk <<= 1) rs += __shfl_xor(rs, msk, 64);
  float rstd = rsqrtf(rs * (1.f / DD) + 1e-6f);
  const float4* rwp = (const float4*)rw;
#pragma unroll
  for (int e = 0; e < 4; ++e) {
    float4 wv = rwp[e * 64 + lane];
    float4 o;
    o.x = v[e].x * rstd * wv.x;
    o.y = v[e].y * rstd * wv.y;
    o.z = v[e].z * rstd * wv.z;
    o.w = v[e].w * rstd * wv.w;
    p[e * 64 + lane] = o;
  }
}

extern "C" void kernel_launch(void* const* d_in, const int* in_sizes, int n_in,
                              void* d_out, int out_size, void* d_ws, size_t ws_size,
                              hipStream_t stream) {
  (void)in_sizes; (void)n_in; (void)out_size;
  const float* x        = (const float*)d_in[0];
  const float* W_lambda = (const float*)d_in[1];
  const float* b_lambda = (const float*)d_in[2];
  const float* W_B      = (const float*)d_in[3];
  const float* W_C      = (const float*)d_in[4];
  const float* W_gate   = (const float*)d_in[5];
  const float* rms_w    = (const float*)d_in[6];
  char* ws = (char*)d_ws;
  __bf16* xb  = (__bf16*)(ws + 0);           // 67108864 B
  __bf16* wg  = (__bf16*)(ws + 67108864);    // 2097152 B
  __bf16* wp  = (__bf16*)(ws + 69206016);    // 65536 B
  float*  lam = (float*)(ws + 69271552);     // 2097152 B
  float*  bx  = (float*)(ws + 71368704);     // 2097152 B
  float*  hs  = (float*)(ws + 73465856);     // 2097152 B
  __bf16* yb  = (__bf16*)(ws + 75563008);    // 67108864 B (optional)
  float*  out = (float*)d_out;
  bool yb16 = ws_size >= (size_t)(75563008ull + 67108864ull);

  k_cvtw<<<(DD * DD / 8 + 2 * NN * DD / 8 + 255) / 256, 256, 0, stream>>>(
      W_gate, W_lambda, W_B, wg, wp);
  k_proj<<<TOK / 128, 256, 0, stream>>>(x, wp, b_lambda, xb, lam, bx);
  k_scan<<<BBATCH * NN, 256, 0, stream>>>(lam, bx, hs);
  if (yb16) {
    k_gemm<1><<<(TOK / 256) * (DD / 256), 512, 0, stream>>>(xb, wg, hs, W_C, nullptr, yb);
    k_norm_b<<<TOK / 4, 256, 0, stream>>>(yb, out, rms_w);
  } else {
    k_gemm<0><<<(TOK / 256) * (DD / 256), 512, 0, stream>>>(xb, wg, hs, W_C, out, nullptr);
    k_norm_f<<<TOK / 4, 256, 0, stream>>>(out, rms_w);
  }
}

// Round 8
// 188.848 us; speedup vs baseline: 2.0028x; 1.0586x over previous
//
#include <hip/hip_runtime.h>

#define DD 1024
#define NN 16
#define SS 4096
#define BBATCH 8
#define TOK (BBATCH*SS)

typedef __attribute__((ext_vector_type(8))) __bf16 bf16x8;
typedef __attribute__((ext_vector_type(4))) __bf16 bf16x4;
typedef __attribute__((ext_vector_type(4))) float f32x4;
typedef unsigned int u32;
typedef unsigned long long u64;

__device__ __forceinline__ void async16(void* lds, const void* g) {
  __builtin_amdgcn_global_load_lds(
      (const __attribute__((address_space(1))) u32*)(u64)(g),
      (__attribute__((address_space(3))) u32*)(u32)(u64)(lds), 16, 0, 0);
}

__device__ __forceinline__ float sigmoidf_(float v) {
  return 1.f / (1.f + __expf(-v));
}

// ---------------- merged weight converts: W_gate, W_lambda, W_B -> bf16 ----------------
__global__ void k_cvtw(const float* __restrict__ wgf, const float* __restrict__ wlf,
                       const float* __restrict__ wbf, __bf16* __restrict__ wg,
                       __bf16* __restrict__ wp) {
  int i = blockIdx.x * blockDim.x + threadIdx.x;
  const int NG = DD * DD / 8, NP = NN * DD / 8;
  const float* src; __bf16* dst;
  if (i < NG)           { src = wgf + (u64)i * 8;            dst = wg + (u64)i * 8; }
  else if (i < NG + NP) { int j = i - NG; src = wlf + j * 8; dst = wp + j * 8; }
  else if (i < NG + 2 * NP) { int j = i - NG - NP; src = wbf + j * 8; dst = wp + NN * DD + j * 8; }
  else return;
  float4 a = *(const float4*)src, b = *(const float4*)(src + 4);
  bf16x8 o;
  o[0] = (__bf16)a.x; o[1] = (__bf16)a.y; o[2] = (__bf16)a.z; o[3] = (__bf16)a.w;
  o[4] = (__bf16)b.x; o[5] = (__bf16)b.y; o[6] = (__bf16)b.z; o[7] = (__bf16)b.w;
  *(bf16x8*)dst = o;
}

// ---------------- projection (x f32 -> bf16 fused): [lam|Bx] = x @ Wproj^T ----------------
__global__ __launch_bounds__(256)
void k_proj(const float* __restrict__ x, const __bf16* __restrict__ wp,
            const float* __restrict__ b_lambda, __bf16* __restrict__ xb,
            float* __restrict__ lam, float* __restrict__ bx) {
  __shared__ __align__(16) __bf16 sA[128 * 32];
  __shared__ __align__(16) __bf16 sB[32 * 32];
  int tid = threadIdx.x;
  int lane = tid & 63, w = tid >> 6;
  int tok0 = blockIdx.x * 128;
  int crow = tid >> 1, cs = (tid & 1) * 2;
  const float* xsrc = x + (u64)(tok0 + crow) * DD + (tid & 1) * 16;
  __bf16* xdst = xb + (u64)(tok0 + crow) * DD + (tid & 1) * 16;
  int sw = (crow & 3) ^ ((crow >> 2) & 3);
  u64 bSrc;
  {
    int u = tid;
    int row = u >> 2, slot = (u & 3) ^ (row & 3);
    bSrc = (u64)((const char*)wp + ((u64)row * DD + slot * 8) * 2);
  }
  f32x4 acc[2][2] = {};
  int r15 = lane & 15, kg = lane >> 4;
  for (int kt = 0; kt < DD / 32; ++kt) {
    float4 a0 = *(const float4*)(xsrc + kt * 32 + 0);
    float4 a1 = *(const float4*)(xsrc + kt * 32 + 4);
    float4 a2 = *(const float4*)(xsrc + kt * 32 + 8);
    float4 a3 = *(const float4*)(xsrc + kt * 32 + 12);
    bf16x8 lo, hi;
    lo[0] = (__bf16)a0.x; lo[1] = (__bf16)a0.y; lo[2] = (__bf16)a0.z; lo[3] = (__bf16)a0.w;
    lo[4] = (__bf16)a1.x; lo[5] = (__bf16)a1.y; lo[6] = (__bf16)a1.z; lo[7] = (__bf16)a1.w;
    hi[0] = (__bf16)a2.x; hi[1] = (__bf16)a2.y; hi[2] = (__bf16)a2.z; hi[3] = (__bf16)a2.w;
    hi[4] = (__bf16)a3.x; hi[5] = (__bf16)a3.y; hi[6] = (__bf16)a3.z; hi[7] = (__bf16)a3.w;
    *(bf16x8*)(xdst + kt * 32) = lo;
    *(bf16x8*)(xdst + kt * 32 + 8) = hi;
    *(bf16x8*)((char*)sA + crow * 64 + ((cs ^ sw) << 4)) = lo;
    *(bf16x8*)((char*)sA + crow * 64 + (((cs + 1) ^ sw) << 4)) = hi;
    if (tid < 128)
      async16((char*)sB + w * 1024, (const void*)(bSrc + kt * 64));
    __syncthreads();
    bf16x8 bfr[2];
#pragma unroll
    for (int nt = 0; nt < 2; ++nt) {
      int brow = nt * 16 + r15;
      bfr[nt] = *(const bf16x8*)((const char*)sB + brow * 64 + ((kg ^ (brow & 3)) << 4));
    }
#pragma unroll
    for (int mt = 0; mt < 2; ++mt) {
      int arow = w * 32 + mt * 16 + r15;
      bf16x8 af = *(const bf16x8*)((const char*)sA + arow * 64 +
                                   ((kg ^ (arow & 3) ^ ((arow >> 2) & 3)) << 4));
#pragma unroll
      for (int nt = 0; nt < 2; ++nt)
        acc[mt][nt] = __builtin_amdgcn_mfma_f32_16x16x32_bf16(af, bfr[nt], acc[mt][nt], 0, 0, 0);
    }
    __syncthreads();
  }
#pragma unroll
  for (int mt = 0; mt < 2; ++mt)
#pragma unroll
    for (int nt = 0; nt < 2; ++nt)
#pragma unroll
      for (int r = 0; r < 4; ++r) {
        int token = tok0 + w * 32 + mt * 16 + kg * 4 + r;
        int j = nt * 16 + r15;
        float v = acc[mt][nt][r];
        if (j < 16) lam[token * NN + j] = sigmoidf_(v + b_lambda[j]);
        else        bx[token * NN + (j - 16)] = v;
      }
}

// ---------------- chunked parallel scan: h_t = lam_t*h_{t-1} + Bx_t ----------------
__global__ __launch_bounds__(256)
void k_scan(const float* __restrict__ lam, const float* __restrict__ bx,
            float* __restrict__ hs) {
  int b = blockIdx.x >> 4, n = blockIdx.x & 15;
  int t = threadIdx.x;
  const int CH = SS / 256;  // 16
  float lv[CH], bv[CH];
  int base = (b * SS + t * CH) * NN + n;
  float a = 1.f, bacc = 0.f;
#pragma unroll
  for (int i = 0; i < CH; ++i) {
    lv[i] = lam[base + i * NN];
    bv[i] = bx[base + i * NN];
    bacc = lv[i] * bacc + bv[i];
    a *= lv[i];
  }
  __shared__ float As[2][256], Bs[2][256];
  As[0][t] = a; Bs[0][t] = bacc;
  __syncthreads();
  int cur = 0;
  for (int off = 1; off < 256; off <<= 1) {
    float a2 = As[cur][t], b2 = Bs[cur][t];
    if (t >= off) {
      float ap = As[cur][t - off], bp = Bs[cur][t - off];
      b2 = b2 + a2 * bp;
      a2 = a2 * ap;
    }
    As[cur ^ 1][t] = a2; Bs[cur ^ 1][t] = b2;
    cur ^= 1;
    __syncthreads();
  }
  float h = (t == 0) ? 0.f : Bs[cur][t - 1];
#pragma unroll
  for (int i = 0; i < CH; ++i) {
    h = lv[i] * h + bv[i];
    hs[base + i * NN] = h;
  }
}

// ---------------- gate GEMM 256x256xK=1024 — 8-phase (4 phases/K-tile, BK=64) ----------------
// K-loop identical to round 7 (verified). Epilogue: Cy via MFMA (hs split hi/lo bf16, wc bf16),
// zero-padded K 16->32 in LDS so the verified 16x16x32 layout applies unchanged.
#define STAGE(tile, M, h) do {                                                    \
    u32 lds0 = (u32)(((((tile) & 1) * 4 + (M) * 2 + (h)) << 14) + tid * 16);      \
    u64 g0 = ((M) ? bBase : aBase) + ((u64)(h) << 18) + (u64)(tile) * 128;        \
    async16(smc + lds0, (const void*)g0);                                         \
    async16(smc + lds0 + 8192, (const void*)(g0 + 131072));                       \
  } while (0)

template<int YB16>
__global__ __launch_bounds__(512, 2)
void k_gemm(const __bf16* __restrict__ xb, const __bf16* __restrict__ wg,
            const float* __restrict__ hs, const float* __restrict__ wc,
            float* __restrict__ outf, __bf16* __restrict__ outb) {
  __shared__ __align__(16) char smc[131072];
  const int tid = threadIdx.x, lane = tid & 63, w = tid >> 6;
  const int r15 = lane & 15, kg = lane >> 4;
  const int wr = w >> 2, wcq = w & 3;       // 2 M-waves x 4 N-waves
  int bid = blockIdx.x;
  int swz = (bid & 7) * 64 + (bid >> 3);    // bijective XCD swizzle (512 % 8 == 0)
  int m = swz >> 2, n = swz & 3;
  const int tok0 = m * 256, n0 = n * 256;
  const int sslot = (tid & 7) ^ ((tid >> 3) & 7);
  const u64 aBase = (u64)(const char*)xb + (u64)(tok0 + (tid >> 3)) * 2048 + (u32)sslot * 16;
  const u64 bBase = (u64)(const char*)wg + (u64)(n0 + (tid >> 3)) * 2048 + (u32)sslot * 16;
  const u32 sxa0 = (u32)(((0 | kg) ^ (r15 & 7)) * 16);
  const u32 sxa1 = (u32)(((4 | kg) ^ (r15 & 7)) * 16);
  const u32 lrB0 = (u32)((wcq & 1) * 64);

  f32x4 acc[8][4] = {};

  // prologue: tile0 (4 halves) + B1h0,B1h1,A1h0 -> vmcnt(6) => tile0 landed
  STAGE(0, 0, 0); STAGE(0, 0, 1); STAGE(0, 1, 0); STAGE(0, 1, 1);
  STAGE(1, 1, 0); STAGE(1, 1, 1); STAGE(1, 0, 0);
  asm volatile("s_waitcnt vmcnt(6)" ::: "memory");
  __builtin_amdgcn_s_barrier();
  asm volatile("" ::: "memory");

  for (int k = 0; k < 16; ++k) {
    const int b = k & 1;
    const char* Ah = smc + (u32)((b * 4 + wr) << 14);
    const char* Bh = smc + (u32)((b * 4 + 2 + (wcq >> 1)) << 14);
    bf16x8 af[8][2], bfr[4][2];
    // ---- P1: read A m0-1 + B all (12 ds) | stage A(k+1)h1 | MFMA m0-1 ----
#pragma unroll
    for (int mt = 0; mt < 2; ++mt) {
      u32 ro = (u32)(mt * 16 + r15) * 128;
      af[mt][0] = *(const bf16x8*)(Ah + ro + sxa0);
      af[mt][1] = *(const bf16x8*)(Ah + ro + sxa1);
    }
#pragma unroll
    for (int nt = 0; nt < 4; ++nt) {
      u32 ro = (lrB0 + (u32)(nt * 16 + r15)) * 128;
      bfr[nt][0] = *(const bf16x8*)(Bh + ro + sxa0);
      bfr[nt][1] = *(const bf16x8*)(Bh + ro + sxa1);
    }
    if (k <= 14) STAGE(k + 1, 0, 1);
    __builtin_amdgcn_s_barrier();
    asm volatile("s_waitcnt lgkmcnt(0)" ::: "memory");
    __builtin_amdgcn_sched_barrier(0);
    __builtin_amdgcn_s_setprio(1);
#pragma unroll
    for (int mt = 0; mt < 2; ++mt)
#pragma unroll
      for (int nt = 0; nt < 4; ++nt) {
        acc[mt][nt] = __builtin_amdgcn_mfma_f32_16x16x32_bf16(af[mt][0], bfr[nt][0], acc[mt][nt], 0, 0, 0);
        acc[mt][nt] = __builtin_amdgcn_mfma_f32_16x16x32_bf16(af[mt][1], bfr[nt][1], acc[mt][nt], 0, 0, 0);
      }
    __builtin_amdgcn_s_setprio(0);
    __builtin_amdgcn_s_barrier();
    asm volatile("" ::: "memory");
    // ---- P2: read A m2-5 (8 ds) | stage B(k+2)h0 | MFMA m2-3 ----
#pragma unroll
    for (int mt = 2; mt < 6; ++mt) {
      u32 ro = (u32)(mt * 16 + r15) * 128;
      af[mt][0] = *(const bf16x8*)(Ah + ro + sxa0);
      af[mt][1] = *(const bf16x8*)(Ah + ro + sxa1);
    }
    if (k <= 13) STAGE(k + 2, 1, 0);
    __builtin_amdgcn_s_barrier();
    asm volatile("s_waitcnt lgkmcnt(0)" ::: "memory");
    __builtin_amdgcn_sched_barrier(0);
    __builtin_amdgcn_s_setprio(1);
#pragma unroll
    for (int mt = 2; mt < 4; ++mt)
#pragma unroll
      for (int nt = 0; nt < 4; ++nt) {
        acc[mt][nt] = __builtin_amdgcn_mfma_f32_16x16x32_bf16(af[mt][0], bfr[nt][0], acc[mt][nt], 0, 0, 0);
        acc[mt][nt] = __builtin_amdgcn_mfma_f32_16x16x32_bf16(af[mt][1], bfr[nt][1], acc[mt][nt], 0, 0, 0);
      }
    __builtin_amdgcn_s_setprio(0);
    __builtin_amdgcn_s_barrier();
    asm volatile("" ::: "memory");
    // ---- P3: read A m6-7 (4 ds) | stage B(k+2)h1 | MFMA m4-5 ----
#pragma unroll
    for (int mt = 6; mt < 8; ++mt) {
      u32 ro = (u32)(mt * 16 + r15) * 128;
      af[mt][0] = *(const bf16x8*)(Ah + ro + sxa0);
      af[mt][1] = *(const bf16x8*)(Ah + ro + sxa1);
    }
    if (k <= 13) STAGE(k + 2, 1, 1);
    __builtin_amdgcn_s_barrier();
    asm volatile("s_waitcnt lgkmcnt(0)" ::: "memory");
    __builtin_amdgcn_sched_barrier(0);
    __builtin_amdgcn_s_setprio(1);
#pragma unroll
    for (int mt = 4; mt < 6; ++mt)
#pragma unroll
      for (int nt = 0; nt < 4; ++nt) {
        acc[mt][nt] = __builtin_amdgcn_mfma_f32_16x16x32_bf16(af[mt][0], bfr[nt][0], acc[mt][nt], 0, 0, 0);
        acc[mt][nt] = __builtin_amdgcn_mfma_f32_16x16x32_bf16(af[mt][1], bfr[nt][1], acc[mt][nt], 0, 0, 0);
      }
    __builtin_amdgcn_s_setprio(0);
    __builtin_amdgcn_s_barrier();
    asm volatile("" ::: "memory");
    // ---- P4: stage A(k+2)h0 | vmcnt | barrier | MFMA m6-7 ----
    if (k <= 13) STAGE(k + 2, 0, 0);
    if (k <= 13)      asm volatile("s_waitcnt vmcnt(6)" ::: "memory");
    else if (k == 14) asm volatile("s_waitcnt vmcnt(0)" ::: "memory");
    __builtin_amdgcn_s_barrier();
    asm volatile("" ::: "memory");
    __builtin_amdgcn_s_setprio(1);
#pragma unroll
    for (int mt = 6; mt < 8; ++mt)
#pragma unroll
      for (int nt = 0; nt < 4; ++nt) {
        acc[mt][nt] = __builtin_amdgcn_mfma_f32_16x16x32_bf16(af[mt][0], bfr[nt][0], acc[mt][nt], 0, 0, 0);
        acc[mt][nt] = __builtin_amdgcn_mfma_f32_16x16x32_bf16(af[mt][1], bfr[nt][1], acc[mt][nt], 0, 0, 0);
      }
    __builtin_amdgcn_s_setprio(0);
  }
  asm volatile("" ::: "memory");

  // ---- epilogue: Cy via MFMA. Tiles (64B rows, k 0-15 real / 16-31 zero, slot^(row&3)):
  //   hsH @0 (16KB), hsL @16KB, wcB @32KB.
  __bf16* hsH = (__bf16*)smc;
  __bf16* hsL = (__bf16*)(smc + 16384);
  __bf16* wcB = (__bf16*)(smc + 32768);
  {
    int row = tid >> 1, half = tid & 1;
    const float* hp = hs + (u64)(tok0 + row) * NN + half * 8;
    const float* wp2 = wc + (u64)(n0 + row) * NN + half * 8;
    float4 h0 = *(const float4*)hp, h1 = *(const float4*)(hp + 4);
    float4 w0 = *(const float4*)wp2, w1 = *(const float4*)(wp2 + 4);
    bf16x8 hh, hl, wb, zz = {};
    float hv[8] = {h0.x, h0.y, h0.z, h0.w, h1.x, h1.y, h1.z, h1.w};
    float wv[8] = {w0.x, w0.y, w0.z, w0.w, w1.x, w1.y, w1.z, w1.w};
#pragma unroll
    for (int e = 0; e < 8; ++e) {
      __bf16 hi = (__bf16)hv[e];
      hh[e] = hi;
      hl[e] = (__bf16)(hv[e] - (float)hi);
      wb[e] = (__bf16)wv[e];
    }
    u32 realOff = (u32)row * 32 + (u32)((half ^ (row & 3)) << 3);
    u32 zeroOff = (u32)row * 32 + (u32)(((2 + half) ^ (row & 3)) << 3);
    *(bf16x8*)(hsH + realOff) = hh;  *(bf16x8*)(hsH + zeroOff) = zz;
    *(bf16x8*)(hsL + realOff) = hl;  *(bf16x8*)(hsL + zeroOff) = zz;
    *(bf16x8*)(wcB + realOff) = wb;  *(bf16x8*)(wcB + zeroOff) = zz;
  }
  __syncthreads();
  bf16x8 bw[4];
#pragma unroll
  for (int nt = 0; nt < 4; ++nt) {
    int row = wcq * 64 + nt * 16 + r15;
    bw[nt] = *(const bf16x8*)(wcB + row * 32 + ((kg ^ (row & 3)) << 3));
  }
  const f32x4 zero4 = {};
#pragma unroll
  for (int mt = 0; mt < 8; ++mt) {
    int arow = wr * 128 + mt * 16 + r15;
    u32 ao = (u32)arow * 32 + (u32)((kg ^ (arow & 3)) << 3);
    bf16x8 ah = *(const bf16x8*)(hsH + ao);
    bf16x8 al = *(const bf16x8*)(hsL + ao);
#pragma unroll
    for (int nt = 0; nt < 4; ++nt) {
      f32x4 cy4 = __builtin_amdgcn_mfma_f32_16x16x32_bf16(al, bw[nt], zero4, 0, 0, 0);
      cy4 = __builtin_amdgcn_mfma_f32_16x16x32_bf16(ah, bw[nt], cy4, 0, 0, 0);
      int j = wcq * 64 + nt * 16 + r15;
#pragma unroll
      for (int r = 0; r < 4; ++r) {
        int i = wr * 128 + mt * 16 + kg * 4 + r;
        float g = sigmoidf_(acc[mt][nt][r]);
        u64 off = (u64)(tok0 + i) * DD + n0 + j;
        if (YB16) outb[off] = (__bf16)(g * cy4[r]);
        else      outf[off] = g * cy4[r];
      }
    }
  }
}

// ---------------- RMSNorm: read y bf16 (ws), write f32 out (coalesced) ----------------
__global__ __launch_bounds__(256)
void k_norm_b(const __bf16* __restrict__ yb, float* __restrict__ out,
              const float* __restrict__ rw) {
  int row = blockIdx.x * 4 + (threadIdx.x >> 6);
  int lane = threadIdx.x & 63;
  const __bf16* yrow = yb + (u64)row * DD;
  bf16x4 v[4];
  float f[16];
  float rs = 0.f;
#pragma unroll
  for (int q = 0; q < 4; ++q) {
    v[q] = *(const bf16x4*)(yrow + q * 256 + lane * 4);
#pragma unroll
    for (int e = 0; e < 4; ++e) {
      f[q * 4 + e] = (float)v[q][e];
      rs += f[q * 4 + e] * f[q * 4 + e];
    }
  }
#pragma unroll
  for (int msk = 1; msk < 64; msk <<= 1) rs += __shfl_xor(rs, msk, 64);
  float rstd = rsqrtf(rs * (1.f / DD) + 1e-6f);
  float* orow = out + (u64)row * DD;
#pragma unroll
  for (int q = 0; q < 4; ++q) {
    float4 wv = *(const float4*)(rw + q * 256 + lane * 4);
    float4 o;
    o.x = f[q * 4 + 0] * rstd * wv.x;
    o.y = f[q * 4 + 1] * rstd * wv.y;
    o.z = f[q * 4 + 2] * rstd * wv.z;
    o.w = f[q * 4 + 3] * rstd * wv.w;
    *(float4*)(orow + q * 256 + lane * 4) = o;
  }
}

// ---------------- RMSNorm fallback: in-place f32 ----------------
__global__ __launch_bounds__(256)
void k_norm_f(float* __restrict__ out, const float* __restrict__ rw) {
  int row = blockIdx.x * 4 + (threadIdx.x >> 6);
  int lane = threadIdx.x & 63;
  float4* p = (float4*)(out + (u64)row * DD);
  float4 v[4];
  float rs = 0.f;
#pragma unroll
  for (int e = 0; e < 4; ++e) {
    v[e] = p[e * 64 + lane];
    rs += v[e].x * v[e].x + v[e].y * v[e].y + v[e].z * v[e].z + v[e].w * v[e].w;
  }
#pragma unroll
  for (int msk = 1; msk < 64; msk <<= 1) rs += __shfl_xor(rs, msk, 64);
  float rstd = rsqrtf(rs * (1.f / DD) + 1e-6f);
  const float4* rwp = (const float4*)rw;
#pragma unroll
  for (int e = 0; e < 4; ++e) {
    float4 wv = rwp[e * 64 + lane];
    float4 o;
    o.x = v[e].x * rstd * wv.x;
    o.y = v[e].y * rstd * wv.y;
    o.z = v[e].z * rstd * wv.z;
    o.w = v[e].w * rstd * wv.w;
    p[e * 64 + lane] = o;
  }
}

extern "C" void kernel_launch(void* const* d_in, const int* in_sizes, int n_in,
                              void* d_out, int out_size, void* d_ws, size_t ws_size,
                              hipStream_t stream) {
  (void)in_sizes; (void)n_in; (void)out_size;
  const float* x        = (const float*)d_in[0];
  const float* W_lambda = (const float*)d_in[1];
  const float* b_lambda = (const float*)d_in[2];
  const float* W_B      = (const float*)d_in[3];
  const float* W_C      = (const float*)d_in[4];
  const float* W_gate   = (const float*)d_in[5];
  const float* rms_w    = (const float*)d_in[6];
  char* ws = (char*)d_ws;
  __bf16* xb  = (__bf16*)(ws + 0);           // 67108864 B
  __bf16* wg  = (__bf16*)(ws + 67108864);    // 2097152 B
  __bf16* wp  = (__bf16*)(ws + 69206016);    // 65536 B
  float*  lam = (float*)(ws + 69271552);     // 2097152 B
  float*  bx  = (float*)(ws + 71368704);     // 2097152 B
  float*  hs  = (float*)(ws + 73465856);     // 2097152 B
  __bf16* yb  = (__bf16*)(ws + 75563008);    // 67108864 B (optional)
  float*  out = (float*)d_out;
  bool yb16 = ws_size >= (size_t)(75563008ull + 67108864ull);

  k_cvtw<<<(DD * DD / 8 + 2 * NN * DD / 8 + 255) / 256, 256, 0, stream>>>(
      W_gate, W_lambda, W_B, wg, wp);
  k_proj<<<TOK / 128, 256, 0, stream>>>(x, wp, b_lambda, xb, lam, bx);
  k_scan<<<BBATCH * NN, 256, 0, stream>>>(lam, bx, hs);
  if (yb16) {
    k_gemm<1><<<(TOK / 256) * (DD / 256), 512, 0, stream>>>(xb, wg, hs, W_C, nullptr, yb);
    k_norm_b<<<TOK / 4, 256, 0, stream>>>(yb, out, rms_w);
  } else {
    k_gemm<0><<<(TOK / 256) * (DD / 256), 512, 0, stream>>>(xb, wg, hs, W_C, out, nullptr);
    k_norm_f<<<TOK / 4, 256, 0, stream>>>(out, rms_w);
  }
}